// Round 13
// baseline (335.903 us; speedup 1.0000x reference)
//
#include <hip/hip_runtime.h>

#define NTOK 8192
#define DIM  512
#define MHID 2048
#define EHID 1024
#define NEXP 8
#define RBLK 64   // tokens per router block

using half_t = _Float16;
typedef _Float16 f16x8 __attribute__((ext_vector_type(8)));
typedef float    f32x16 __attribute__((ext_vector_type(16)));

#define MFMA32(a, b, c) __builtin_amdgcn_mfma_f32_32x32x16_f16((a), (b), (c), 0, 0, 0)

typedef const __attribute__((address_space(1))) void* gas_ptr;
typedef __attribute__((address_space(3))) void*       las_ptr;
__device__ __forceinline__ void gl16(const void* g, void* l) {
    __builtin_amdgcn_global_load_lds((gas_ptr)g, (las_ptr)l, 16, 0, 0);
}

__device__ __forceinline__ float gelu_exact(float v) {
    return 0.5f * v * (1.0f + erff(v * 0.70710678118654752f));
}

// all-threads-return block sum over 4 waves (256 threads)
__device__ __forceinline__ float block_sum4(float v, float* red, int tid) {
#pragma unroll
    for (int off = 32; off; off >>= 1) v += __shfl_down(v, off);
    if ((tid & 63) == 0) red[tid >> 6] = v;
    __syncthreads();
    float r = red[0] + red[1] + red[2] + red[3];
    __syncthreads();
    return r;
}

// ---------------- LN1 + fp16 hi/lo split (+ folds cnt zeroing) ----------------
__global__ __launch_bounds__(256) void ln1_split_kernel(
    const float* __restrict__ x, const float* __restrict__ g, const float* __restrict__ b,
    half_t* __restrict__ xh, half_t* __restrict__ xl, int* __restrict__ cnt)
{
    const int row = blockIdx.x, tid = threadIdx.x;
    if (row == 0) cnt[tid] = 0;   // zero all 256 padded slots (8 experts * stride 32)
    __shared__ float red[4];
    const size_t base = (size_t)row * DIM;
    float2 v = reinterpret_cast<const float2*>(x + base)[tid];
    float mean = block_sum4(v.x + v.y, red, tid) * (1.0f / DIM);
    float d0 = v.x - mean, d1 = v.y - mean;
    float var = block_sum4(d0 * d0 + d1 * d1, red, tid) * (1.0f / DIM);
    float rstd = rsqrtf(var + 1e-5f);
    int d = tid * 2;
    float y0 = d0 * rstd * g[d]     + b[d];
    float y1 = d1 * rstd * g[d + 1] + b[d + 1];
    half_t h0 = (half_t)y0, h1 = (half_t)y1;
    xh[base + d] = h0;  xh[base + d + 1] = h1;
    xl[base + d]     = (half_t)(y0 - (float)h0);
    xl[base + d + 1] = (half_t)(y1 - (float)h1);
}

// ---- ALL weight transposes in ONE launch: [R][C] -> [C][R], f16 (optional lo split) ----
__global__ void transpose_all_kernel(
    const float* __restrict__ w1, const float* __restrict__ w2,
    const float* __restrict__ ew1, const float* __restrict__ ew2,
    half_t* __restrict__ w1t_h, half_t* __restrict__ w1t_l,
    half_t* __restrict__ w2t_h, half_t* __restrict__ w2t_l,
    half_t* __restrict__ ew1t, half_t* __restrict__ ew2t)
{
    int bb = blockIdx.x;
    const float* in; half_t* oh; half_t* ol = (half_t*)0;
    int R, C, cx, cy; size_t mo = 0;
    if (bb < 1024)      { in = w1;  oh = w1t_h; ol = w1t_l; R = 512;  C = 2048; cx = bb & 63; cy = bb >> 6; }
    else if (bb < 2048) { bb -= 1024; in = w2;  oh = w2t_h; ol = w2t_l; R = 2048; C = 512; cx = bb & 15; cy = bb >> 4; }
    else if (bb < 6144) { bb -= 2048; int e = bb >> 9, r = bb & 511;
                          in = ew1; oh = ew1t; R = 512;  C = 1024; mo = (size_t)e * R * C; cx = r & 31; cy = r >> 5; }
    else                { bb -= 6144; int e = bb >> 9, r = bb & 511;
                          in = ew2; oh = ew2t; R = 1024; C = 512;  mo = (size_t)e * R * C; cx = r & 15; cy = r >> 4; }
    __shared__ float t[32][33];
    const int c0 = cx * 32, r0 = cy * 32;
    const int tx = threadIdx.x, ty = threadIdx.y;
    for (int i = ty; i < 32; i += 8) t[i][tx] = in[mo + (size_t)(r0 + i) * C + c0 + tx];
    __syncthreads();
    for (int i = ty; i < 32; i += 8) {
        float v = t[tx][i];
        size_t o = mo + (size_t)(c0 + i) * R + r0 + tx;
        half_t h = (half_t)v;
        oh[o] = h;
        if (ol) ol[o] = (half_t)(v - (float)h);
    }
}

// ======== split-3 f16 MFMA GEMM, 256-row tile, 8 waves, counted-vmcnt, 2 barriers/step ========
// (r9 structure — empirically at this structure's ceiling; five schedule variants tied)
template <int EPI, int NREP>
__global__ __launch_bounds__(512, 2) void gemm8_kernel(
    const half_t* __restrict__ A0, const half_t* __restrict__ A1,
    const half_t* __restrict__ B0, const half_t* __restrict__ B1,
    const float* __restrict__ bias,
    float* __restrict__ Cf0, float* __restrict__ Cf1,
    half_t* __restrict__ Ch, half_t* __restrict__ Cl,
    int Nc, int K, int Ktile)
{
    constexpr int BN    = NREP * 128;
    constexpr int LOADS = 4 + 2 * NREP;            // 16B chunks staged per thread per K-step
    constexpr int TOT   = 16384 + NREP * 8192;     // half_t elems per LDS buffer
    __shared__ __align__(16) half_t lds[2 * TOT];

    const int m0 = blockIdx.x * 256, n0 = blockIdx.y * BN;
    const int kbeg = blockIdx.z * Ktile;
    float* Cf = blockIdx.z ? Cf1 : Cf0;
    const int tid = threadIdx.x;
    const int lane = tid & 63, wid = tid >> 6;
    const int wr = wid >> 2, wc = wid & 3;         // 2 x 4 wave grid
    const int l31 = lane & 31, l5 = lane >> 5;

    const half_t* gsrc[LOADS];
    {
        const half_t* A0p = A0 + (size_t)m0 * K + kbeg;
        const half_t* A1p = A1 + (size_t)m0 * K + kbeg;
        const half_t* B0p = B0 + (size_t)n0 * K + kbeg;
        const half_t* B1p = B1 + (size_t)n0 * K + kbeg;
#pragma unroll
        for (int i = 0; i < LOADS; i++) {
            int c = tid + 512 * i;
            const half_t* base; int cm;
            if (c < 1024)                  { base = A0p; cm = c; }
            else if (c < 2048)             { base = A1p; cm = c - 1024; }
            else if (c < 2048 + NREP * 512){ base = B0p; cm = c - 2048; }
            else                           { base = B1p; cm = c - 2048 - NREP * 512; }
            int r = cm >> 2, ss = (cm & 3) ^ ((r >> 1) & 3);
            gsrc[i] = base + (size_t)r * K + ss * 8;
        }
    }

    int oa[4][2], ob[NREP][2];
#pragma unroll
    for (int m = 0; m < 4; m++)
#pragma unroll
        for (int kh = 0; kh < 2; kh++) {
            int ra = wr * 128 + m * 32 + l31;
            oa[m][kh] = ra * 32 + (((l5 + 2 * kh) ^ ((ra >> 1) & 3)) << 3);
        }
#pragma unroll
    for (int n = 0; n < NREP; n++)
#pragma unroll
        for (int kh = 0; kh < 2; kh++) {
            int rb = wc * (NREP * 32) + n * 32 + l31;
            ob[n][kh] = rb * 32 + (((l5 + 2 * kh) ^ ((rb >> 1) & 3)) << 3);
        }

    f32x16 acc[4][NREP];
#pragma unroll
    for (int m = 0; m < 4; m++)
#pragma unroll
        for (int n = 0; n < NREP; n++)
#pragma unroll
            for (int q = 0; q < 16; q++) acc[m][n][q] = 0.f;

    auto stage = [&](int bsel, int kof) {
#pragma unroll
        for (int i = 0; i < LOADS; i++)
            gl16(gsrc[i] + kof, &lds[bsel * TOT + (tid + 512 * i) * 8]);
    };
    auto compute = [&](int p) {
        const half_t* buf = &lds[p ? TOT : 0];
        __builtin_amdgcn_s_setprio(1);
#pragma unroll
        for (int kh = 0; kh < 2; kh++) {
            f16x8 ah[4], al[4], bh[NREP], bl[NREP];
#pragma unroll
            for (int m = 0; m < 4; m++) {
                ah[m] = *(const f16x8*)(buf + oa[m][kh]);
                al[m] = *(const f16x8*)(buf + 8192 + oa[m][kh]);
            }
#pragma unroll
            for (int n = 0; n < NREP; n++) {
                bh[n] = *(const f16x8*)(buf + 16384 + ob[n][kh]);
                bl[n] = *(const f16x8*)(buf + 16384 + BN * 32 + ob[n][kh]);
            }
#pragma unroll
            for (int m = 0; m < 4; m++)
#pragma unroll
                for (int n = 0; n < NREP; n++) {
                    acc[m][n] = MFMA32(ah[m], bh[n], acc[m][n]);
                    acc[m][n] = MFMA32(al[m], bh[n], acc[m][n]);
                    acc[m][n] = MFMA32(ah[m], bl[n], acc[m][n]);
                }
        }
        __builtin_amdgcn_s_setprio(0);
    };

    const int nsteps = Ktile / 32;
    stage(0, 0);
#pragma unroll 1
    for (int s = 0; s < nsteps - 1; ++s) {
        stage((s + 1) & 1, (s + 1) * 32);
        if constexpr (NREP == 2) asm volatile("s_waitcnt vmcnt(8)" ::: "memory");
        else                     asm volatile("s_waitcnt vmcnt(6)" ::: "memory");
        __builtin_amdgcn_s_barrier();
        compute(s & 1);
        __builtin_amdgcn_s_barrier();
    }
    asm volatile("s_waitcnt vmcnt(0)" ::: "memory");
    __builtin_amdgcn_s_barrier();
    compute((nsteps - 1) & 1);

    const int er = 4 * l5;
#pragma unroll
    for (int m = 0; m < 4; m++)
#pragma unroll
        for (int n = 0; n < NREP; n++) {
            int cc = n0 + wc * (NREP * 32) + n * 32 + l31;
            float bv = (EPI == 1) ? bias[cc] : 0.f;
#pragma unroll
            for (int reg = 0; reg < 16; reg++) {
                int rr = m0 + wr * 128 + m * 32 + er + 8 * (reg >> 2) + (reg & 3);
                float v = acc[m][n][reg] + bv;
                size_t o = (size_t)rr * Nc + cc;
                if (EPI == 1) {
                    float ge = gelu_exact(v);
                    half_t h = (half_t)ge;
                    Ch[o] = h;
                    Cl[o] = (half_t)(ge - (float)h);
                } else {
                    Cf[o] = v;
                }
            }
        }
}

// ======== FUSED: x2 = x+(p0+p1+b2); x3 = LN2(x2)+x2 (in regs) -> x3h + router ========
// 128 blocks x 256 thr; each wave owns 16 tokens, one token at a time fully in
// registers (lane covers dims lane*8..lane*8+7).  Router weight slices hoisted to
// VGPRs; logits reduced via 64-lane shuffles.  Eliminates the x3f round trip.
__global__ __launch_bounds__(256) void resln2_router_kernel(
    const float* __restrict__ x, const float* __restrict__ p0,
    const float* __restrict__ p1, const float* __restrict__ b2,
    const float* __restrict__ g, const float* __restrict__ b,
    const float* __restrict__ wrm,
    half_t* __restrict__ x3h,
    int* __restrict__ cnt, int* __restrict__ aid, float* __restrict__ gate)
{
    __shared__ float wl[NEXP][DIM];
    __shared__ int   texp[RBLK * 2];
    __shared__ float tgate[RBLK * 2];
    __shared__ int   lslot[RBLK * 2];
    __shared__ int   lcnt[NEXP], lbase[NEXP];
    const int tid = threadIdx.x;
    for (int i = tid; i < NEXP * DIM / 4; i += 256)
        reinterpret_cast<float4*>(&wl[0][0])[i] = reinterpret_cast<const float4*>(wrm)[i];
    if (tid < NEXP) lcnt[tid] = 0;
    __syncthreads();
    const int w = tid >> 6, lane = tid & 63;
    const int d0 = lane * 8;
    float wle[NEXP][8];
#pragma unroll
    for (int e = 0; e < NEXP; e++)
#pragma unroll
        for (int j = 0; j < 8; j++) wle[e][j] = wl[e][d0 + j];
    float gg[8], bb[8], b2v[8];
#pragma unroll
    for (int j = 0; j < 8; j++) { gg[j] = g[d0 + j]; bb[j] = b[d0 + j]; b2v[j] = b2[d0 + j]; }
#pragma unroll 1
    for (int t = 0; t < RBLK / 4; ++t) {
        const int lt = w * (RBLK / 4) + t;
        const int token = blockIdx.x * RBLK + lt;
        const size_t base = (size_t)token * DIM + d0;
        float z[8];
#pragma unroll
        for (int h = 0; h < 2; h++) {
            float4 xa = reinterpret_cast<const float4*>(x + base)[h];
            float4 pa = reinterpret_cast<const float4*>(p0 + base)[h];
            float4 qa = reinterpret_cast<const float4*>(p1 + base)[h];
            z[4 * h + 0] = xa.x + pa.x + qa.x + b2v[4 * h + 0];
            z[4 * h + 1] = xa.y + pa.y + qa.y + b2v[4 * h + 1];
            z[4 * h + 2] = xa.z + pa.z + qa.z + b2v[4 * h + 2];
            z[4 * h + 3] = xa.w + pa.w + qa.w + b2v[4 * h + 3];
        }
        float s = 0.f;
#pragma unroll
        for (int j = 0; j < 8; j++) s += z[j];
#pragma unroll
        for (int off = 32; off; off >>= 1) s += __shfl_xor(s, off);
        const float mean = s * (1.0f / DIM);
        float vs = 0.f;
#pragma unroll
        for (int j = 0; j < 8; j++) { float d = z[j] - mean; vs += d * d; }
#pragma unroll
        for (int off = 32; off; off >>= 1) vs += __shfl_xor(vs, off);
        const float rstd = rsqrtf(vs * (1.0f / DIM) + 1e-5f);
        float y[8];
        f16x8 hv;
#pragma unroll
        for (int j = 0; j < 8; j++) {
            y[j] = (z[j] - mean) * rstd * gg[j] + bb[j] + z[j];
            hv[j] = (half_t)y[j];
        }
        *reinterpret_cast<f16x8*>(x3h + base) = hv;
        float a[NEXP];
#pragma unroll
        for (int e = 0; e < NEXP; e++) {
            a[e] = 0.f;
#pragma unroll
            for (int j = 0; j < 8; j++) a[e] += y[j] * wle[e][j];
        }
#pragma unroll
        for (int e = 0; e < NEXP; e++)
#pragma unroll
            for (int off = 32; off; off >>= 1) a[e] += __shfl_xor(a[e], off);
        if (lane == 0) {
            int i1 = 0; float v1 = a[0];
#pragma unroll
            for (int e = 1; e < NEXP; e++) if (a[e] > v1) { v1 = a[e]; i1 = e; }
            int i2 = -1; float v2 = -3.4e38f;
#pragma unroll
            for (int e = 0; e < NEXP; e++) if (e != i1 && a[e] > v2) { v2 = a[e]; i2 = e; }
            float e2 = expf(v2 - v1);
            float g1 = 1.0f / (1.0f + e2);
            texp[lt * 2]     = i1; tgate[lt * 2]     = g1;
            texp[lt * 2 + 1] = i2; tgate[lt * 2 + 1] = 1.0f - g1;
        }
    }
    __syncthreads();
    if (tid < RBLK * 2) lslot[tid] = atomicAdd(&lcnt[texp[tid]], 1);
    __syncthreads();
    if (tid < NEXP) lbase[tid] = atomicAdd(&cnt[tid * 32], lcnt[tid]);
    __syncthreads();
    if (tid < RBLK * 2) {
        const int e = texp[tid];
        const int asg = blockIdx.x * (RBLK * 2) + tid;   // token*2 + k
        aid[e * NTOK + lbase[e] + lslot[tid]] = asg;
        gate[asg] = tgate[tid];
    }
}

// ======== expert GEMMs, 8-wave 256x256-tile counted-vmcnt structure ========
// BM=256 (rowmap-gathered), BN=256, 8 waves 4(M)x2(N), per-wave 64x128, BK=32.
// LDS/buffer: A 256x32 (16KB) + B 256x32 (16KB) = 32KB; x2 dbuf = 64KB -> 2 blocks/CU.
// 4 gl16/thread/step; counted vmcnt(4); 2 barriers/step; 16 MFMA : 12 ds_read per wave.
// EG=1: He[a] = gelu(X[a>>1] @ W^T + eb).  EG=2: Ye[a] = (Hin[a] @ W^T + eb) * gate[a].
template <int EG, int KDIM, int AROWSHIFT>
__global__ __launch_bounds__(512, 2) void egemm8_kernel(
    const half_t* __restrict__ Ain,
    const half_t* __restrict__ W,
    const float* __restrict__ ebias,
    const int* __restrict__ cnt, const int* __restrict__ aid,
    const float* __restrict__ gate,
    half_t* __restrict__ Oh,
    float* __restrict__ Of,
    int Nc)
{
    const int ntPerE = Nc / 256;                 // 4 (EG1) or 2 (EG2)
    const int bid = blockIdx.x;
    const int e   = bid / (32 * ntPerE);
    const int rem = bid % (32 * ntPerE);
    const int mt  = rem / ntPerE, nt = rem % ntPerE;
    const int ne  = cnt[e * 32];
    if (mt * 256 >= ne) return;

    constexpr int TOT = 8192 + 8192;             // elems/buffer: A 256x32 + B 256x32
    __shared__ __align__(16) half_t lds[2 * TOT];
    __shared__ int rowmap[256];
    const int tid = threadIdx.x;
    if (tid < 256) {
        int slot = mt * 256 + tid;
        rowmap[tid] = (slot < ne) ? aid[e * NTOK + slot] : -1;
    }
    __syncthreads();

    const int lane = tid & 63, wid = tid >> 6;
    const int wr = wid >> 1, wc = wid & 1;       // 4(M) x 2(N)
    const int l31 = lane & 31, l5 = lane >> 5;

    // staging: 2048 chunks of 16B per buffer; thread stages 4 (c = tid + 512*i).
    const half_t* gsrc[4];
    const half_t* Wb = W + (size_t)e * Nc * KDIM;
#pragma unroll
    for (int i = 0; i < 4; i++) {
        int c = tid + 512 * i;
        if (c < 1024) {
            int r = c >> 2, ss = (c & 3) ^ ((r >> 1) & 3);
            int a = rowmap[r];
            gsrc[i] = Ain + (size_t)(a >= 0 ? (a >> AROWSHIFT) : 0) * KDIM + ss * 8;
        } else {
            int cb = c - 1024;
            int r = cb >> 2, ss = (cb & 3) ^ ((r >> 1) & 3);
            gsrc[i] = Wb + (size_t)(nt * 256 + r) * KDIM + ss * 8;
        }
    }

    int oa[2][2], ob[4][2];
#pragma unroll
    for (int m = 0; m < 2; m++)
#pragma unroll
        for (int kh = 0; kh < 2; kh++) {
            int ra = wr * 64 + m * 32 + l31;
            oa[m][kh] = ra * 32 + (((l5 + 2 * kh) ^ ((ra >> 1) & 3)) << 3);
        }
#pragma unroll
    for (int n = 0; n < 4; n++)
#pragma unroll
        for (int kh = 0; kh < 2; kh++) {
            int rb = wc * 128 + n * 32 + l31;
            ob[n][kh] = 8192 + rb * 32 + (((l5 + 2 * kh) ^ ((rb >> 1) & 3)) << 3);
        }

    f32x16 acc[2][4];
#pragma unroll
    for (int m = 0; m < 2; m++)
#pragma unroll
        for (int n = 0; n < 4; n++)
#pragma unroll
            for (int q = 0; q < 16; q++) acc[m][n][q] = 0.f;

    auto stage = [&](int bsel, int kof) {
#pragma unroll
        for (int i = 0; i < 4; i++)
            gl16(gsrc[i] + kof, &lds[bsel * TOT + (tid + 512 * i) * 8]);
    };
    auto compute = [&](int p) {
        const half_t* buf = &lds[p ? TOT : 0];
        __builtin_amdgcn_s_setprio(1);
#pragma unroll
        for (int kh = 0; kh < 2; kh++) {
            f16x8 a0 = *(const f16x8*)(buf + oa[0][kh]);
            f16x8 a1 = *(const f16x8*)(buf + oa[1][kh]);
            f16x8 bf[4];
#pragma unroll
            for (int n = 0; n < 4; n++) bf[n] = *(const f16x8*)(buf + ob[n][kh]);
#pragma unroll
            for (int n = 0; n < 4; n++) {
                acc[0][n] = MFMA32(a0, bf[n], acc[0][n]);
                acc[1][n] = MFMA32(a1, bf[n], acc[1][n]);
            }
        }
        __builtin_amdgcn_s_setprio(0);
    };

    const int nsteps = KDIM / 32;
    stage(0, 0);
#pragma unroll 1
    for (int s = 0; s < nsteps - 1; ++s) {
        stage((s + 1) & 1, (s + 1) * 32);
        asm volatile("s_waitcnt vmcnt(4)" ::: "memory");
        __builtin_amdgcn_s_barrier();
        compute(s & 1);
        __builtin_amdgcn_s_barrier();
    }
    asm volatile("s_waitcnt vmcnt(0)" ::: "memory");
    __builtin_amdgcn_s_barrier();
    compute((nsteps - 1) & 1);

    const int er = 4 * l5;
#pragma unroll
    for (int m = 0; m < 2; m++)
#pragma unroll
        for (int reg = 0; reg < 16; reg++) {
            int rloc = wr * 64 + m * 32 + er + 8 * (reg >> 2) + (reg & 3);
            int a = rowmap[rloc];
            if (a >= 0) {
#pragma unroll
                for (int n = 0; n < 4; n++) {
                    int cc = nt * 256 + wc * 128 + n * 32 + l31;
                    float v = acc[m][n][reg] + ebias[e * Nc + cc];
                    if (EG == 1) {
                        Oh[(size_t)a * Nc + cc] = (half_t)gelu_exact(v);
                    } else {
                        Of[(size_t)a * Nc + cc] = v * gate[a];
                    }
                }
            }
        }
}

// ---------------- combine two expert outputs per token + final LN ----------------
__global__ __launch_bounds__(256) void combine_lnf_kernel(
    const float* __restrict__ Ye, const float* __restrict__ g, const float* __restrict__ b,
    float* __restrict__ out)
{
    const int t = blockIdx.x, tid = threadIdx.x;
    __shared__ float red[4];
    float2 y0 = reinterpret_cast<const float2*>(Ye + (size_t)(2 * t) * DIM)[tid];
    float2 y1 = reinterpret_cast<const float2*>(Ye + (size_t)(2 * t + 1) * DIM)[tid];
    float z0 = y0.x + y1.x, z1 = y0.y + y1.y;
    float mean = block_sum4(z0 + z1, red, tid) * (1.0f / DIM);
    float d0 = z0 - mean, d1 = z1 - mean;
    float var = block_sum4(d0 * d0 + d1 * d1, red, tid) * (1.0f / DIM);
    float rstd = rsqrtf(var + 1e-5f);
    int d = tid * 2;
    out[(size_t)t * DIM + d]     = d0 * rstd * g[d]     + b[d];
    out[(size_t)t * DIM + d + 1] = d1 * rstd * g[d + 1] + b[d + 1];
    if (t == 0 && tid == 0) out[(size_t)NTOK * DIM] = 0.f;  // aux_loss
}

extern "C" void kernel_launch(void* const* d_in, const int* in_sizes, int n_in,
                              void* d_out, int out_size, void* d_ws, size_t ws_size,
                              hipStream_t stream)
{
    (void)in_sizes; (void)n_in; (void)out_size; (void)ws_size;
    const float* x    = (const float*)d_in[0];
    const float* ln1g = (const float*)d_in[1];
    const float* ln1b = (const float*)d_in[2];
    const float* w1   = (const float*)d_in[3];
    const float* b1   = (const float*)d_in[4];
    const float* w2   = (const float*)d_in[5];
    const float* b2   = (const float*)d_in[6];
    const float* ln2g = (const float*)d_in[7];
    const float* ln2b = (const float*)d_in[8];
    const float* wrm  = (const float*)d_in[9];
    const float* ew1  = (const float*)d_in[10];
    const float* eb1  = (const float*)d_in[11];
    const float* ew2  = (const float*)d_in[12];
    const float* eb2  = (const float*)d_in[13];
    const float* lnfg = (const float*)d_in[14];
    const float* lnfb = (const float*)d_in[15];
    float* out = (float*)d_out;

    char* w = (char*)d_ws;
    size_t off = 0;
    auto take = [&](size_t bytes) {
        char* p = w + off;
        off += bytes;
        off = (off + 255) & ~(size_t)255;
        return p;
    };
    half_t* xh_h  = (half_t*)take((size_t)NTOK * DIM * 2);   // also split-K partial p1 (f32, 16MB)
    half_t* xh_l  = (half_t*)take((size_t)NTOK * DIM * 2);
    half_t* w1t_h = (half_t*)take((size_t)DIM * MHID * 2);
    half_t* w1t_l = (half_t*)take((size_t)DIM * MHID * 2);
    half_t* w2t_h = (half_t*)take((size_t)MHID * DIM * 2);
    half_t* w2t_l = (half_t*)take((size_t)MHID * DIM * 2);
    char*   big   = take((size_t)NTOK * MHID * 2 * 2);        // 64 MiB: a1 hi/lo, later He + Ye
    half_t* a1h   = (half_t*)big;
    half_t* a1l   = (half_t*)(big + (size_t)NTOK * MHID * 2);
    half_t* heh   = (half_t*)big;                              // alias (a1 dead after gemm8<0>)
    float*  yef   = (float*)(big + (size_t)NTOK * MHID * 2);   // alias
    float*  p0f   = (float*)take((size_t)NTOK * DIM * 4);      // split-K partial p0
    half_t* x3h   = (half_t*)take((size_t)NTOK * DIM * 2);
    half_t* ew1t  = (half_t*)take((size_t)NEXP * DIM * EHID * 2);
    half_t* ew2t  = (half_t*)take((size_t)NEXP * EHID * DIM * 2);
    int*    cnt   = (int*)take(1024);                          // 8 experts, 128 B apart
    int*    aid   = (int*)take((size_t)NEXP * NTOK * 4);
    float*  gate  = (float*)take((size_t)NTOK * 2 * 4);

    float* p0 = p0f;
    float* p1 = (float*)xh_h;   // xh_h+xh_l = contiguous 16 MB, dead after gemm8<1>

    ln1_split_kernel<<<NTOK, 256, 0, stream>>>(x, ln1g, ln1b, xh_h, xh_l, cnt);
    transpose_all_kernel<<<10240, dim3(32, 8), 0, stream>>>(
        w1, w2, ew1, ew2, w1t_h, w1t_l, w2t_h, w2t_l, ew1t, ew2t);
    // MLP GEMM1: [8192x512] @ [512x2048], gelu, split out.  256x256 tile, 8 waves.
    gemm8_kernel<1, 2><<<dim3(NTOK / 256, MHID / 256, 1), 512, 0, stream>>>(
        xh_h, xh_l, w1t_h, w1t_l, b1, (float*)0, (float*)0, a1h, a1l, MHID, DIM, DIM);
    // MLP GEMM2: [8192x2048] @ [2048x512], 256x128 tile, split-K=2 raw partials
    gemm8_kernel<0, 1><<<dim3(NTOK / 256, DIM / 128, 2), 512, 0, stream>>>(
        a1h, a1l, w2t_h, w2t_l, (const float*)0, p0, p1, (half_t*)0, (half_t*)0, DIM, MHID, MHID / 2);
    // fused residual + LN2 + router (x3 lives in registers; writes x3h only)
    resln2_router_kernel<<<NTOK / RBLK, 256, 0, stream>>>(
        x, p0, p1, b2, ln2g, ln2b, wrm, x3h, cnt, aid, gate);
    // expert GEMM1: 8 experts x 32 m-tiles x 4 n-tiles (256x256 tiles)
    egemm8_kernel<1, DIM, 1><<<NEXP * 32 * (EHID / 256), 512, 0, stream>>>(
        x3h, ew1t, eb1, cnt, aid, (const float*)0, heh, (float*)0, EHID);
    // expert GEMM2: 8 experts x 32 m-tiles x 2 n-tiles
    egemm8_kernel<2, EHID, 0><<<NEXP * 32 * (DIM / 256), 512, 0, stream>>>(
        heh, ew2t, eb2, cnt, aid, gate, (half_t*)0, yef, DIM);
    combine_lnf_kernel<<<NTOK, 256, 0, stream>>>(yef, lnfg, lnfb, out);
}

// Round 14
// 310.955 us; speedup vs baseline: 1.0802x; 1.0802x over previous
//
#include <hip/hip_runtime.h>

#define NTOK 8192
#define DIM  512
#define MHID 2048
#define EHID 1024
#define NEXP 8
#define RBLK 64   // tokens per router block

using half_t = _Float16;
typedef _Float16 f16x8 __attribute__((ext_vector_type(8)));
typedef float    f32x16 __attribute__((ext_vector_type(16)));

#define MFMA32(a, b, c) __builtin_amdgcn_mfma_f32_32x32x16_f16((a), (b), (c), 0, 0, 0)

typedef const __attribute__((address_space(1))) void* gas_ptr;
typedef __attribute__((address_space(3))) void*       las_ptr;
__device__ __forceinline__ void gl16(const void* g, void* l) {
    __builtin_amdgcn_global_load_lds((gas_ptr)g, (las_ptr)l, 16, 0, 0);
}

__device__ __forceinline__ float gelu_exact(float v) {
    return 0.5f * v * (1.0f + erff(v * 0.70710678118654752f));
}

// all-threads-return block sum over 4 waves (256 threads)
__device__ __forceinline__ float block_sum4(float v, float* red, int tid) {
#pragma unroll
    for (int off = 32; off; off >>= 1) v += __shfl_down(v, off);
    if ((tid & 63) == 0) red[tid >> 6] = v;
    __syncthreads();
    float r = red[0] + red[1] + red[2] + red[3];
    __syncthreads();
    return r;
}

// ---------------- LN1 + fp16 hi/lo split (+ folds cnt zeroing) ----------------
__global__ __launch_bounds__(256) void ln1_split_kernel(
    const float* __restrict__ x, const float* __restrict__ g, const float* __restrict__ b,
    half_t* __restrict__ xh, half_t* __restrict__ xl, int* __restrict__ cnt)
{
    const int row = blockIdx.x, tid = threadIdx.x;
    if (row == 0) cnt[tid] = 0;   // zero all 256 padded slots (8 experts * stride 32)
    __shared__ float red[4];
    const size_t base = (size_t)row * DIM;
    float2 v = reinterpret_cast<const float2*>(x + base)[tid];
    float mean = block_sum4(v.x + v.y, red, tid) * (1.0f / DIM);
    float d0 = v.x - mean, d1 = v.y - mean;
    float var = block_sum4(d0 * d0 + d1 * d1, red, tid) * (1.0f / DIM);
    float rstd = rsqrtf(var + 1e-5f);
    int d = tid * 2;
    float y0 = d0 * rstd * g[d]     + b[d];
    float y1 = d1 * rstd * g[d + 1] + b[d + 1];
    half_t h0 = (half_t)y0, h1 = (half_t)y1;
    xh[base + d] = h0;  xh[base + d + 1] = h1;
    xl[base + d]     = (half_t)(y0 - (float)h0);
    xl[base + d + 1] = (half_t)(y1 - (float)h1);
}

// ---- ALL weight transposes in ONE launch: [R][C] -> [C][R], f16 (optional lo split) ----
__global__ void transpose_all_kernel(
    const float* __restrict__ w1, const float* __restrict__ w2,
    const float* __restrict__ ew1, const float* __restrict__ ew2,
    half_t* __restrict__ w1t_h, half_t* __restrict__ w1t_l,
    half_t* __restrict__ w2t_h, half_t* __restrict__ w2t_l,
    half_t* __restrict__ ew1t, half_t* __restrict__ ew2t)
{
    int bb = blockIdx.x;
    const float* in; half_t* oh; half_t* ol = (half_t*)0;
    int R, C, cx, cy; size_t mo = 0;
    if (bb < 1024)      { in = w1;  oh = w1t_h; ol = w1t_l; R = 512;  C = 2048; cx = bb & 63; cy = bb >> 6; }
    else if (bb < 2048) { bb -= 1024; in = w2;  oh = w2t_h; ol = w2t_l; R = 2048; C = 512; cx = bb & 15; cy = bb >> 4; }
    else if (bb < 6144) { bb -= 2048; int e = bb >> 9, r = bb & 511;
                          in = ew1; oh = ew1t; R = 512;  C = 1024; mo = (size_t)e * R * C; cx = r & 31; cy = r >> 5; }
    else                { bb -= 6144; int e = bb >> 9, r = bb & 511;
                          in = ew2; oh = ew2t; R = 1024; C = 512;  mo = (size_t)e * R * C; cx = r & 15; cy = r >> 4; }
    __shared__ float t[32][33];
    const int c0 = cx * 32, r0 = cy * 32;
    const int tx = threadIdx.x, ty = threadIdx.y;
    for (int i = ty; i < 32; i += 8) t[i][tx] = in[mo + (size_t)(r0 + i) * C + c0 + tx];
    __syncthreads();
    for (int i = ty; i < 32; i += 8) {
        float v = t[tx][i];
        size_t o = mo + (size_t)(c0 + i) * R + r0 + tx;
        half_t h = (half_t)v;
        oh[o] = h;
        if (ol) ol[o] = (half_t)(v - (float)h);
    }
}

// ======== split-3 f16 MFMA GEMM, 256-row tile, 8 waves, counted-vmcnt, 2 barriers/step ========
// (r9 structure — empirically at this structure's ceiling; five schedule variants tied)
template <int EPI, int NREP>
__global__ __launch_bounds__(512, 2) void gemm8_kernel(
    const half_t* __restrict__ A0, const half_t* __restrict__ A1,
    const half_t* __restrict__ B0, const half_t* __restrict__ B1,
    const float* __restrict__ bias,
    float* __restrict__ Cf0, float* __restrict__ Cf1,
    half_t* __restrict__ Ch, half_t* __restrict__ Cl,
    int Nc, int K, int Ktile)
{
    constexpr int BN    = NREP * 128;
    constexpr int LOADS = 4 + 2 * NREP;            // 16B chunks staged per thread per K-step
    constexpr int TOT   = 16384 + NREP * 8192;     // half_t elems per LDS buffer
    __shared__ __align__(16) half_t lds[2 * TOT];

    const int m0 = blockIdx.x * 256, n0 = blockIdx.y * BN;
    const int kbeg = blockIdx.z * Ktile;
    float* Cf = blockIdx.z ? Cf1 : Cf0;
    const int tid = threadIdx.x;
    const int lane = tid & 63, wid = tid >> 6;
    const int wr = wid >> 2, wc = wid & 3;         // 2 x 4 wave grid
    const int l31 = lane & 31, l5 = lane >> 5;

    const half_t* gsrc[LOADS];
    {
        const half_t* A0p = A0 + (size_t)m0 * K + kbeg;
        const half_t* A1p = A1 + (size_t)m0 * K + kbeg;
        const half_t* B0p = B0 + (size_t)n0 * K + kbeg;
        const half_t* B1p = B1 + (size_t)n0 * K + kbeg;
#pragma unroll
        for (int i = 0; i < LOADS; i++) {
            int c = tid + 512 * i;
            const half_t* base; int cm;
            if (c < 1024)                  { base = A0p; cm = c; }
            else if (c < 2048)             { base = A1p; cm = c - 1024; }
            else if (c < 2048 + NREP * 512){ base = B0p; cm = c - 2048; }
            else                           { base = B1p; cm = c - 2048 - NREP * 512; }
            int r = cm >> 2, ss = (cm & 3) ^ ((r >> 1) & 3);
            gsrc[i] = base + (size_t)r * K + ss * 8;
        }
    }

    int oa[4][2], ob[NREP][2];
#pragma unroll
    for (int m = 0; m < 4; m++)
#pragma unroll
        for (int kh = 0; kh < 2; kh++) {
            int ra = wr * 128 + m * 32 + l31;
            oa[m][kh] = ra * 32 + (((l5 + 2 * kh) ^ ((ra >> 1) & 3)) << 3);
        }
#pragma unroll
    for (int n = 0; n < NREP; n++)
#pragma unroll
        for (int kh = 0; kh < 2; kh++) {
            int rb = wc * (NREP * 32) + n * 32 + l31;
            ob[n][kh] = rb * 32 + (((l5 + 2 * kh) ^ ((rb >> 1) & 3)) << 3);
        }

    f32x16 acc[4][NREP];
#pragma unroll
    for (int m = 0; m < 4; m++)
#pragma unroll
        for (int n = 0; n < NREP; n++)
#pragma unroll
            for (int q = 0; q < 16; q++) acc[m][n][q] = 0.f;

    auto stage = [&](int bsel, int kof) {
#pragma unroll
        for (int i = 0; i < LOADS; i++)
            gl16(gsrc[i] + kof, &lds[bsel * TOT + (tid + 512 * i) * 8]);
    };
    auto compute = [&](int p) {
        const half_t* buf = &lds[p ? TOT : 0];
        __builtin_amdgcn_s_setprio(1);
#pragma unroll
        for (int kh = 0; kh < 2; kh++) {
            f16x8 ah[4], al[4], bh[NREP], bl[NREP];
#pragma unroll
            for (int m = 0; m < 4; m++) {
                ah[m] = *(const f16x8*)(buf + oa[m][kh]);
                al[m] = *(const f16x8*)(buf + 8192 + oa[m][kh]);
            }
#pragma unroll
            for (int n = 0; n < NREP; n++) {
                bh[n] = *(const f16x8*)(buf + 16384 + ob[n][kh]);
                bl[n] = *(const f16x8*)(buf + 16384 + BN * 32 + ob[n][kh]);
            }
#pragma unroll
            for (int m = 0; m < 4; m++)
#pragma unroll
                for (int n = 0; n < NREP; n++) {
                    acc[m][n] = MFMA32(ah[m], bh[n], acc[m][n]);
                    acc[m][n] = MFMA32(al[m], bh[n], acc[m][n]);
                    acc[m][n] = MFMA32(ah[m], bl[n], acc[m][n]);
                }
        }
        __builtin_amdgcn_s_setprio(0);
    };

    const int nsteps = Ktile / 32;
    stage(0, 0);
#pragma unroll 1
    for (int s = 0; s < nsteps - 1; ++s) {
        stage((s + 1) & 1, (s + 1) * 32);
        if constexpr (NREP == 2) asm volatile("s_waitcnt vmcnt(8)" ::: "memory");
        else                     asm volatile("s_waitcnt vmcnt(6)" ::: "memory");
        __builtin_amdgcn_s_barrier();
        compute(s & 1);
        __builtin_amdgcn_s_barrier();
    }
    asm volatile("s_waitcnt vmcnt(0)" ::: "memory");
    __builtin_amdgcn_s_barrier();
    compute((nsteps - 1) & 1);

    const int er = 4 * l5;
#pragma unroll
    for (int m = 0; m < 4; m++)
#pragma unroll
        for (int n = 0; n < NREP; n++) {
            int cc = n0 + wc * (NREP * 32) + n * 32 + l31;
            float bv = (EPI == 1) ? bias[cc] : 0.f;
#pragma unroll
            for (int reg = 0; reg < 16; reg++) {
                int rr = m0 + wr * 128 + m * 32 + er + 8 * (reg >> 2) + (reg & 3);
                float v = acc[m][n][reg] + bv;
                size_t o = (size_t)rr * Nc + cc;
                if (EPI == 1) {
                    float ge = gelu_exact(v);
                    half_t h = (half_t)ge;
                    Ch[o] = h;
                    Cl[o] = (half_t)(ge - (float)h);
                } else {
                    Cf[o] = v;
                }
            }
        }
}

// ======== FUSED: x2 = x+(p0+p1+b2); x3 = LN2(x2)+x2 (in regs) -> x3h + router ========
__global__ __launch_bounds__(256) void resln2_router_kernel(
    const float* __restrict__ x, const float* __restrict__ p0,
    const float* __restrict__ p1, const float* __restrict__ b2,
    const float* __restrict__ g, const float* __restrict__ b,
    const float* __restrict__ wrm,
    half_t* __restrict__ x3h,
    int* __restrict__ cnt, int* __restrict__ aid, float* __restrict__ gate)
{
    __shared__ float wl[NEXP][DIM];
    __shared__ int   texp[RBLK * 2];
    __shared__ float tgate[RBLK * 2];
    __shared__ int   lslot[RBLK * 2];
    __shared__ int   lcnt[NEXP], lbase[NEXP];
    const int tid = threadIdx.x;
    for (int i = tid; i < NEXP * DIM / 4; i += 256)
        reinterpret_cast<float4*>(&wl[0][0])[i] = reinterpret_cast<const float4*>(wrm)[i];
    if (tid < NEXP) lcnt[tid] = 0;
    __syncthreads();
    const int w = tid >> 6, lane = tid & 63;
    const int d0 = lane * 8;
    float wle[NEXP][8];
#pragma unroll
    for (int e = 0; e < NEXP; e++)
#pragma unroll
        for (int j = 0; j < 8; j++) wle[e][j] = wl[e][d0 + j];
    float gg[8], bb[8], b2v[8];
#pragma unroll
    for (int j = 0; j < 8; j++) { gg[j] = g[d0 + j]; bb[j] = b[d0 + j]; b2v[j] = b2[d0 + j]; }
#pragma unroll 1
    for (int t = 0; t < RBLK / 4; ++t) {
        const int lt = w * (RBLK / 4) + t;
        const int token = blockIdx.x * RBLK + lt;
        const size_t base = (size_t)token * DIM + d0;
        float z[8];
#pragma unroll
        for (int h = 0; h < 2; h++) {
            float4 xa = reinterpret_cast<const float4*>(x + base)[h];
            float4 pa = reinterpret_cast<const float4*>(p0 + base)[h];
            float4 qa = reinterpret_cast<const float4*>(p1 + base)[h];
            z[4 * h + 0] = xa.x + pa.x + qa.x + b2v[4 * h + 0];
            z[4 * h + 1] = xa.y + pa.y + qa.y + b2v[4 * h + 1];
            z[4 * h + 2] = xa.z + pa.z + qa.z + b2v[4 * h + 2];
            z[4 * h + 3] = xa.w + pa.w + qa.w + b2v[4 * h + 3];
        }
        float s = 0.f;
#pragma unroll
        for (int j = 0; j < 8; j++) s += z[j];
#pragma unroll
        for (int off = 32; off; off >>= 1) s += __shfl_xor(s, off);
        const float mean = s * (1.0f / DIM);
        float vs = 0.f;
#pragma unroll
        for (int j = 0; j < 8; j++) { float d = z[j] - mean; vs += d * d; }
#pragma unroll
        for (int off = 32; off; off >>= 1) vs += __shfl_xor(vs, off);
        const float rstd = rsqrtf(vs * (1.0f / DIM) + 1e-5f);
        float y[8];
        f16x8 hv;
#pragma unroll
        for (int j = 0; j < 8; j++) {
            y[j] = (z[j] - mean) * rstd * gg[j] + bb[j] + z[j];
            hv[j] = (half_t)y[j];
        }
        *reinterpret_cast<f16x8*>(x3h + base) = hv;
        float a[NEXP];
#pragma unroll
        for (int e = 0; e < NEXP; e++) {
            a[e] = 0.f;
#pragma unroll
            for (int j = 0; j < 8; j++) a[e] += y[j] * wle[e][j];
        }
#pragma unroll
        for (int e = 0; e < NEXP; e++)
#pragma unroll
            for (int off = 32; off; off >>= 1) a[e] += __shfl_xor(a[e], off);
        if (lane == 0) {
            int i1 = 0; float v1 = a[0];
#pragma unroll
            for (int e = 1; e < NEXP; e++) if (a[e] > v1) { v1 = a[e]; i1 = e; }
            int i2 = -1; float v2 = -3.4e38f;
#pragma unroll
            for (int e = 0; e < NEXP; e++) if (e != i1 && a[e] > v2) { v2 = a[e]; i2 = e; }
            float e2 = expf(v2 - v1);
            float g1 = 1.0f / (1.0f + e2);
            texp[lt * 2]     = i1; tgate[lt * 2]     = g1;
            texp[lt * 2 + 1] = i2; tgate[lt * 2 + 1] = 1.0f - g1;
        }
    }
    __syncthreads();
    if (tid < RBLK * 2) lslot[tid] = atomicAdd(&lcnt[texp[tid]], 1);
    __syncthreads();
    if (tid < NEXP) lbase[tid] = atomicAdd(&cnt[tid * 32], lcnt[tid]);
    __syncthreads();
    if (tid < RBLK * 2) {
        const int e = texp[tid];
        const int asg = blockIdx.x * (RBLK * 2) + tid;   // token*2 + k
        aid[e * NTOK + lbase[e] + lslot[tid]] = asg;
        gate[asg] = tgate[tid];
    }
}

// ======== expert GEMMs: 4-wave 128x128-tile counted-vmcnt, HIGH-TLP variant ========
// BM=128 (rowmap-gathered), BN=128, 4 waves 2(M)x2(N), per-wave 64x64, BK=32.
// LDS/buffer: A 128x32 (8KB) + B 128x32 (8KB) = 16KB; x2 dbuf = 32KB -> 4-5 blocks/CU.
// 4 gl16/thread/step; counted vmcnt(4); 2 barriers/step.  Small tiles quarter the
// expert-imbalance quantum and quadruple block-level latency hiding (gather A-loads
// are scattered -> latency-bound; TLP is the lever, r12 post-mortem).
// EG=1: He[a] = gelu(X[a>>1] @ W^T + eb).  EG=2: Ye[a] = (Hin[a] @ W^T + eb) * gate[a].
template <int EG, int KDIM, int AROWSHIFT>
__global__ __launch_bounds__(256, 4) void egemm4_kernel(
    const half_t* __restrict__ Ain,
    const half_t* __restrict__ W,
    const float* __restrict__ ebias,
    const int* __restrict__ cnt, const int* __restrict__ aid,
    const float* __restrict__ gate,
    half_t* __restrict__ Oh,
    float* __restrict__ Of,
    int Nc)
{
    const int ntPerE = Nc / 128;                 // 8 (EG1) or 4 (EG2)
    const int bid = blockIdx.x;
    const int e   = bid / (64 * ntPerE);
    const int rem = bid % (64 * ntPerE);
    const int mt  = rem / ntPerE, nt = rem % ntPerE;
    const int ne  = cnt[e * 32];
    if (mt * 128 >= ne) return;

    constexpr int TOT = 4096 + 4096;             // elems/buffer: A 128x32 + B 128x32
    __shared__ __align__(16) half_t lds[2 * TOT];
    __shared__ int rowmap[128];
    const int tid = threadIdx.x;
    if (tid < 128) {
        int slot = mt * 128 + tid;
        rowmap[tid] = (slot < ne) ? aid[e * NTOK + slot] : -1;
    }
    __syncthreads();

    const int lane = tid & 63, wid = tid >> 6;
    const int wr = wid >> 1, wc = wid & 1;       // 2(M) x 2(N)
    const int l31 = lane & 31, l5 = lane >> 5;

    // staging: 1024 chunks of 16B per buffer; thread stages 4 (c = tid + 256*i).
    const half_t* gsrc[4];
    const half_t* Wb = W + (size_t)e * Nc * KDIM;
#pragma unroll
    for (int i = 0; i < 4; i++) {
        int c = tid + 256 * i;
        if (c < 512) {
            int r = c >> 2, ss = (c & 3) ^ ((r >> 1) & 3);
            int a = rowmap[r];
            gsrc[i] = Ain + (size_t)(a >= 0 ? (a >> AROWSHIFT) : 0) * KDIM + ss * 8;
        } else {
            int cb = c - 512;
            int r = cb >> 2, ss = (cb & 3) ^ ((r >> 1) & 3);
            gsrc[i] = Wb + (size_t)(nt * 128 + r) * KDIM + ss * 8;
        }
    }

    int oa[2][2], ob[2][2];
#pragma unroll
    for (int m = 0; m < 2; m++)
#pragma unroll
        for (int kh = 0; kh < 2; kh++) {
            int ra = wr * 64 + m * 32 + l31;
            oa[m][kh] = ra * 32 + (((l5 + 2 * kh) ^ ((ra >> 1) & 3)) << 3);
        }
#pragma unroll
    for (int n = 0; n < 2; n++)
#pragma unroll
        for (int kh = 0; kh < 2; kh++) {
            int rb = wc * 64 + n * 32 + l31;
            ob[n][kh] = 4096 + rb * 32 + (((l5 + 2 * kh) ^ ((rb >> 1) & 3)) << 3);
        }

    f32x16 acc[2][2];
#pragma unroll
    for (int m = 0; m < 2; m++)
#pragma unroll
        for (int n = 0; n < 2; n++)
#pragma unroll
            for (int q = 0; q < 16; q++) acc[m][n][q] = 0.f;

    auto stage = [&](int bsel, int kof) {
#pragma unroll
        for (int i = 0; i < 4; i++)
            gl16(gsrc[i] + kof, &lds[bsel * TOT + (tid + 256 * i) * 8]);
    };
    auto compute = [&](int p) {
        const half_t* buf = &lds[p ? TOT : 0];
        __builtin_amdgcn_s_setprio(1);
#pragma unroll
        for (int kh = 0; kh < 2; kh++) {
            f16x8 a0 = *(const f16x8*)(buf + oa[0][kh]);
            f16x8 a1 = *(const f16x8*)(buf + oa[1][kh]);
            f16x8 b0 = *(const f16x8*)(buf + ob[0][kh]);
            f16x8 b1 = *(const f16x8*)(buf + ob[1][kh]);
            acc[0][0] = MFMA32(a0, b0, acc[0][0]);
            acc[0][1] = MFMA32(a0, b1, acc[0][1]);
            acc[1][0] = MFMA32(a1, b0, acc[1][0]);
            acc[1][1] = MFMA32(a1, b1, acc[1][1]);
        }
        __builtin_amdgcn_s_setprio(0);
    };

    const int nsteps = KDIM / 32;
    stage(0, 0);
#pragma unroll 1
    for (int s = 0; s < nsteps - 1; ++s) {
        stage((s + 1) & 1, (s + 1) * 32);
        asm volatile("s_waitcnt vmcnt(4)" ::: "memory");
        __builtin_amdgcn_s_barrier();
        compute(s & 1);
        __builtin_amdgcn_s_barrier();
    }
    asm volatile("s_waitcnt vmcnt(0)" ::: "memory");
    __builtin_amdgcn_s_barrier();
    compute((nsteps - 1) & 1);

    const int er = 4 * l5;
#pragma unroll
    for (int m = 0; m < 2; m++)
#pragma unroll
        for (int reg = 0; reg < 16; reg++) {
            int rloc = wr * 64 + m * 32 + er + 8 * (reg >> 2) + (reg & 3);
            int a = rowmap[rloc];
            if (a >= 0) {
#pragma unroll
                for (int n = 0; n < 2; n++) {
                    int cc = nt * 128 + wc * 64 + n * 32 + l31;
                    float v = acc[m][n][reg] + ebias[e * Nc + cc];
                    if (EG == 1) {
                        Oh[(size_t)a * Nc + cc] = (half_t)gelu_exact(v);
                    } else {
                        Of[(size_t)a * Nc + cc] = v * gate[a];
                    }
                }
            }
        }
}

// ---------------- combine two expert outputs per token + final LN ----------------
__global__ __launch_bounds__(256) void combine_lnf_kernel(
    const float* __restrict__ Ye, const float* __restrict__ g, const float* __restrict__ b,
    float* __restrict__ out)
{
    const int t = blockIdx.x, tid = threadIdx.x;
    __shared__ float red[4];
    float2 y0 = reinterpret_cast<const float2*>(Ye + (size_t)(2 * t) * DIM)[tid];
    float2 y1 = reinterpret_cast<const float2*>(Ye + (size_t)(2 * t + 1) * DIM)[tid];
    float z0 = y0.x + y1.x, z1 = y0.y + y1.y;
    float mean = block_sum4(z0 + z1, red, tid) * (1.0f / DIM);
    float d0 = z0 - mean, d1 = z1 - mean;
    float var = block_sum4(d0 * d0 + d1 * d1, red, tid) * (1.0f / DIM);
    float rstd = rsqrtf(var + 1e-5f);
    int d = tid * 2;
    out[(size_t)t * DIM + d]     = d0 * rstd * g[d]     + b[d];
    out[(size_t)t * DIM + d + 1] = d1 * rstd * g[d + 1] + b[d + 1];
    if (t == 0 && tid == 0) out[(size_t)NTOK * DIM] = 0.f;  // aux_loss
}

extern "C" void kernel_launch(void* const* d_in, const int* in_sizes, int n_in,
                              void* d_out, int out_size, void* d_ws, size_t ws_size,
                              hipStream_t stream)
{
    (void)in_sizes; (void)n_in; (void)out_size; (void)ws_size;
    const float* x    = (const float*)d_in[0];
    const float* ln1g = (const float*)d_in[1];
    const float* ln1b = (const float*)d_in[2];
    const float* w1   = (const float*)d_in[3];
    const float* b1   = (const float*)d_in[4];
    const float* w2   = (const float*)d_in[5];
    const float* b2   = (const float*)d_in[6];
    const float* ln2g = (const float*)d_in[7];
    const float* ln2b = (const float*)d_in[8];
    const float* wrm  = (const float*)d_in[9];
    const float* ew1  = (const float*)d_in[10];
    const float* eb1  = (const float*)d_in[11];
    const float* ew2  = (const float*)d_in[12];
    const float* eb2  = (const float*)d_in[13];
    const float* lnfg = (const float*)d_in[14];
    const float* lnfb = (const float*)d_in[15];
    float* out = (float*)d_out;

    char* w = (char*)d_ws;
    size_t off = 0;
    auto take = [&](size_t bytes) {
        char* p = w + off;
        off += bytes;
        off = (off + 255) & ~(size_t)255;
        return p;
    };
    half_t* xh_h  = (half_t*)take((size_t)NTOK * DIM * 2);   // also split-K partial p1 (f32, 16MB)
    half_t* xh_l  = (half_t*)take((size_t)NTOK * DIM * 2);
    half_t* w1t_h = (half_t*)take((size_t)DIM * MHID * 2);
    half_t* w1t_l = (half_t*)take((size_t)DIM * MHID * 2);
    half_t* w2t_h = (half_t*)take((size_t)MHID * DIM * 2);
    half_t* w2t_l = (half_t*)take((size_t)MHID * DIM * 2);
    char*   big   = take((size_t)NTOK * MHID * 2 * 2);        // 64 MiB: a1 hi/lo, later He + Ye
    half_t* a1h   = (half_t*)big;
    half_t* a1l   = (half_t*)(big + (size_t)NTOK * MHID * 2);
    half_t* heh   = (half_t*)big;                              // alias (a1 dead after gemm8<0>)
    float*  yef   = (float*)(big + (size_t)NTOK * MHID * 2);   // alias
    float*  p0f   = (float*)take((size_t)NTOK * DIM * 4);      // split-K partial p0
    half_t* x3h   = (half_t*)take((size_t)NTOK * DIM * 2);
    half_t* ew1t  = (half_t*)take((size_t)NEXP * DIM * EHID * 2);
    half_t* ew2t  = (half_t*)take((size_t)NEXP * EHID * DIM * 2);
    int*    cnt   = (int*)take(1024);                          // 8 experts, 128 B apart
    int*    aid   = (int*)take((size_t)NEXP * NTOK * 4);
    float*  gate  = (float*)take((size_t)NTOK * 2 * 4);

    float* p0 = p0f;
    float* p1 = (float*)xh_h;   // xh_h+xh_l = contiguous 16 MB, dead after gemm8<1>

    ln1_split_kernel<<<NTOK, 256, 0, stream>>>(x, ln1g, ln1b, xh_h, xh_l, cnt);
    transpose_all_kernel<<<10240, dim3(32, 8), 0, stream>>>(
        w1, w2, ew1, ew2, w1t_h, w1t_l, w2t_h, w2t_l, ew1t, ew2t);
    // MLP GEMM1: [8192x512] @ [512x2048], gelu, split out.  256x256 tile, 8 waves.
    gemm8_kernel<1, 2><<<dim3(NTOK / 256, MHID / 256, 1), 512, 0, stream>>>(
        xh_h, xh_l, w1t_h, w1t_l, b1, (float*)0, (float*)0, a1h, a1l, MHID, DIM, DIM);
    // MLP GEMM2: [8192x2048] @ [2048x512], 256x128 tile, split-K=2 raw partials
    gemm8_kernel<0, 1><<<dim3(NTOK / 256, DIM / 128, 2), 512, 0, stream>>>(
        a1h, a1l, w2t_h, w2t_l, (const float*)0, p0, p1, (half_t*)0, (half_t*)0, DIM, MHID, MHID / 2);
    // fused residual + LN2 + router (x3 lives in registers; writes x3h only)
    resln2_router_kernel<<<NTOK / RBLK, 256, 0, stream>>>(
        x, p0, p1, b2, ln2g, ln2b, wrm, x3h, cnt, aid, gate);
    // expert GEMM1: 8 experts x 64 m-tiles x 8 n-tiles (128x128 tiles, 4-5 blocks/CU)
    egemm4_kernel<1, DIM, 1><<<NEXP * 64 * (EHID / 128), 256, 0, stream>>>(
        x3h, ew1t, eb1, cnt, aid, (const float*)0, heh, (float*)0, EHID);
    // expert GEMM2: 8 experts x 64 m-tiles x 4 n-tiles
    egemm4_kernel<2, EHID, 0><<<NEXP * 64 * (DIM / 128), 256, 0, stream>>>(
        heh, ew2t, eb2, cnt, aid, gate, (half_t*)0, yef, DIM);
    combine_lnf_kernel<<<NTOK, 256, 0, stream>>>(yef, lnfg, lnfb, out);
}

// Round 15
// 306.115 us; speedup vs baseline: 1.0973x; 1.0158x over previous
//
#include <hip/hip_runtime.h>

#define NTOK 8192
#define DIM  512
#define MHID 2048
#define EHID 1024
#define NEXP 8
#define RBLK 64   // tokens per router block

using half_t = _Float16;
typedef _Float16 f16x8 __attribute__((ext_vector_type(8)));
typedef float    f32x16 __attribute__((ext_vector_type(16)));

#define MFMA32(a, b, c) __builtin_amdgcn_mfma_f32_32x32x16_f16((a), (b), (c), 0, 0, 0)

typedef const __attribute__((address_space(1))) void* gas_ptr;
typedef __attribute__((address_space(3))) void*       las_ptr;
__device__ __forceinline__ void gl16(const void* g, void* l) {
    __builtin_amdgcn_global_load_lds((gas_ptr)g, (las_ptr)l, 16, 0, 0);
}

__device__ __forceinline__ float gelu_exact(float v) {
    return 0.5f * v * (1.0f + erff(v * 0.70710678118654752f));
}

// all-threads-return block sum over 4 waves (256 threads)
__device__ __forceinline__ float block_sum4(float v, float* red, int tid) {
#pragma unroll
    for (int off = 32; off; off >>= 1) v += __shfl_down(v, off);
    if ((tid & 63) == 0) red[tid >> 6] = v;
    __syncthreads();
    float r = red[0] + red[1] + red[2] + red[3];
    __syncthreads();
    return r;
}

// ---------------- LN1 + fp16 hi/lo split (+ folds cnt zeroing) ----------------
__global__ __launch_bounds__(256) void ln1_split_kernel(
    const float* __restrict__ x, const float* __restrict__ g, const float* __restrict__ b,
    half_t* __restrict__ xh, half_t* __restrict__ xl, int* __restrict__ cnt)
{
    const int row = blockIdx.x, tid = threadIdx.x;
    if (row == 0) cnt[tid] = 0;   // zero all 256 padded slots (8 experts * stride 32)
    __shared__ float red[4];
    const size_t base = (size_t)row * DIM;
    float2 v = reinterpret_cast<const float2*>(x + base)[tid];
    float mean = block_sum4(v.x + v.y, red, tid) * (1.0f / DIM);
    float d0 = v.x - mean, d1 = v.y - mean;
    float var = block_sum4(d0 * d0 + d1 * d1, red, tid) * (1.0f / DIM);
    float rstd = rsqrtf(var + 1e-5f);
    int d = tid * 2;
    float y0 = d0 * rstd * g[d]     + b[d];
    float y1 = d1 * rstd * g[d + 1] + b[d + 1];
    half_t h0 = (half_t)y0, h1 = (half_t)y1;
    xh[base + d] = h0;  xh[base + d + 1] = h1;
    xl[base + d]     = (half_t)(y0 - (float)h0);
    xl[base + d + 1] = (half_t)(y1 - (float)h1);
}

// ---- ALL weight transposes in ONE launch: [R][C] -> [C][R], f16 (optional lo split) ----
__global__ void transpose_all_kernel(
    const float* __restrict__ w1, const float* __restrict__ w2,
    const float* __restrict__ ew1, const float* __restrict__ ew2,
    half_t* __restrict__ w1t_h, half_t* __restrict__ w1t_l,
    half_t* __restrict__ w2t_h, half_t* __restrict__ w2t_l,
    half_t* __restrict__ ew1t, half_t* __restrict__ ew2t)
{
    int bb = blockIdx.x;
    const float* in; half_t* oh; half_t* ol = (half_t*)0;
    int R, C, cx, cy; size_t mo = 0;
    if (bb < 1024)      { in = w1;  oh = w1t_h; ol = w1t_l; R = 512;  C = 2048; cx = bb & 63; cy = bb >> 6; }
    else if (bb < 2048) { bb -= 1024; in = w2;  oh = w2t_h; ol = w2t_l; R = 2048; C = 512; cx = bb & 15; cy = bb >> 4; }
    else if (bb < 6144) { bb -= 2048; int e = bb >> 9, r = bb & 511;
                          in = ew1; oh = ew1t; R = 512;  C = 1024; mo = (size_t)e * R * C; cx = r & 31; cy = r >> 5; }
    else                { bb -= 6144; int e = bb >> 9, r = bb & 511;
                          in = ew2; oh = ew2t; R = 1024; C = 512;  mo = (size_t)e * R * C; cx = r & 15; cy = r >> 4; }
    __shared__ float t[32][33];
    const int c0 = cx * 32, r0 = cy * 32;
    const int tx = threadIdx.x, ty = threadIdx.y;
    for (int i = ty; i < 32; i += 8) t[i][tx] = in[mo + (size_t)(r0 + i) * C + c0 + tx];
    __syncthreads();
    for (int i = ty; i < 32; i += 8) {
        float v = t[tx][i];
        size_t o = mo + (size_t)(c0 + i) * R + r0 + tx;
        half_t h = (half_t)v;
        oh[o] = h;
        if (ol) ol[o] = (half_t)(v - (float)h);
    }
}

// ======== split-3 f16 MFMA GEMM, 256-row tile, 8 waves, counted-vmcnt, 2 barriers/step ========
// (r9 structure — empirically at this structure's ceiling; five schedule variants tied)
template <int EPI, int NREP>
__global__ __launch_bounds__(512, 2) void gemm8_kernel(
    const half_t* __restrict__ A0, const half_t* __restrict__ A1,
    const half_t* __restrict__ B0, const half_t* __restrict__ B1,
    const float* __restrict__ bias,
    float* __restrict__ Cf0, float* __restrict__ Cf1,
    half_t* __restrict__ Ch, half_t* __restrict__ Cl,
    int Nc, int K, int Ktile)
{
    constexpr int BN    = NREP * 128;
    constexpr int LOADS = 4 + 2 * NREP;            // 16B chunks staged per thread per K-step
    constexpr int TOT   = 16384 + NREP * 8192;     // half_t elems per LDS buffer
    __shared__ __align__(16) half_t lds[2 * TOT];

    const int m0 = blockIdx.x * 256, n0 = blockIdx.y * BN;
    const int kbeg = blockIdx.z * Ktile;
    float* Cf = blockIdx.z ? Cf1 : Cf0;
    const int tid = threadIdx.x;
    const int lane = tid & 63, wid = tid >> 6;
    const int wr = wid >> 2, wc = wid & 3;         // 2 x 4 wave grid
    const int l31 = lane & 31, l5 = lane >> 5;

    const half_t* gsrc[LOADS];
    {
        const half_t* A0p = A0 + (size_t)m0 * K + kbeg;
        const half_t* A1p = A1 + (size_t)m0 * K + kbeg;
        const half_t* B0p = B0 + (size_t)n0 * K + kbeg;
        const half_t* B1p = B1 + (size_t)n0 * K + kbeg;
#pragma unroll
        for (int i = 0; i < LOADS; i++) {
            int c = tid + 512 * i;
            const half_t* base; int cm;
            if (c < 1024)                  { base = A0p; cm = c; }
            else if (c < 2048)             { base = A1p; cm = c - 1024; }
            else if (c < 2048 + NREP * 512){ base = B0p; cm = c - 2048; }
            else                           { base = B1p; cm = c - 2048 - NREP * 512; }
            int r = cm >> 2, ss = (cm & 3) ^ ((r >> 1) & 3);
            gsrc[i] = base + (size_t)r * K + ss * 8;
        }
    }

    int oa[4][2], ob[NREP][2];
#pragma unroll
    for (int m = 0; m < 4; m++)
#pragma unroll
        for (int kh = 0; kh < 2; kh++) {
            int ra = wr * 128 + m * 32 + l31;
            oa[m][kh] = ra * 32 + (((l5 + 2 * kh) ^ ((ra >> 1) & 3)) << 3);
        }
#pragma unroll
    for (int n = 0; n < NREP; n++)
#pragma unroll
        for (int kh = 0; kh < 2; kh++) {
            int rb = wc * (NREP * 32) + n * 32 + l31;
            ob[n][kh] = rb * 32 + (((l5 + 2 * kh) ^ ((rb >> 1) & 3)) << 3);
        }

    f32x16 acc[4][NREP];
#pragma unroll
    for (int m = 0; m < 4; m++)
#pragma unroll
        for (int n = 0; n < NREP; n++)
#pragma unroll
            for (int q = 0; q < 16; q++) acc[m][n][q] = 0.f;

    auto stage = [&](int bsel, int kof) {
#pragma unroll
        for (int i = 0; i < LOADS; i++)
            gl16(gsrc[i] + kof, &lds[bsel * TOT + (tid + 512 * i) * 8]);
    };
    auto compute = [&](int p) {
        const half_t* buf = &lds[p ? TOT : 0];
        __builtin_amdgcn_s_setprio(1);
#pragma unroll
        for (int kh = 0; kh < 2; kh++) {
            f16x8 ah[4], al[4], bh[NREP], bl[NREP];
#pragma unroll
            for (int m = 0; m < 4; m++) {
                ah[m] = *(const f16x8*)(buf + oa[m][kh]);
                al[m] = *(const f16x8*)(buf + 8192 + oa[m][kh]);
            }
#pragma unroll
            for (int n = 0; n < NREP; n++) {
                bh[n] = *(const f16x8*)(buf + 16384 + ob[n][kh]);
                bl[n] = *(const f16x8*)(buf + 16384 + BN * 32 + ob[n][kh]);
            }
#pragma unroll
            for (int m = 0; m < 4; m++)
#pragma unroll
                for (int n = 0; n < NREP; n++) {
                    acc[m][n] = MFMA32(ah[m], bh[n], acc[m][n]);
                    acc[m][n] = MFMA32(al[m], bh[n], acc[m][n]);
                    acc[m][n] = MFMA32(ah[m], bl[n], acc[m][n]);
                }
        }
        __builtin_amdgcn_s_setprio(0);
    };

    const int nsteps = Ktile / 32;
    stage(0, 0);
#pragma unroll 1
    for (int s = 0; s < nsteps - 1; ++s) {
        stage((s + 1) & 1, (s + 1) * 32);
        if constexpr (NREP == 2) asm volatile("s_waitcnt vmcnt(8)" ::: "memory");
        else                     asm volatile("s_waitcnt vmcnt(6)" ::: "memory");
        __builtin_amdgcn_s_barrier();
        compute(s & 1);
        __builtin_amdgcn_s_barrier();
    }
    asm volatile("s_waitcnt vmcnt(0)" ::: "memory");
    __builtin_amdgcn_s_barrier();
    compute((nsteps - 1) & 1);

    const int er = 4 * l5;
#pragma unroll
    for (int m = 0; m < 4; m++)
#pragma unroll
        for (int n = 0; n < NREP; n++) {
            int cc = n0 + wc * (NREP * 32) + n * 32 + l31;
            float bv = (EPI == 1) ? bias[cc] : 0.f;
#pragma unroll
            for (int reg = 0; reg < 16; reg++) {
                int rr = m0 + wr * 128 + m * 32 + er + 8 * (reg >> 2) + (reg & 3);
                float v = acc[m][n][reg] + bv;
                size_t o = (size_t)rr * Nc + cc;
                if (EPI == 1) {
                    float ge = gelu_exact(v);
                    half_t h = (half_t)ge;
                    Ch[o] = h;
                    Cl[o] = (half_t)(ge - (float)h);
                } else {
                    Cf[o] = v;
                }
            }
        }
}

// ======== FUSED: x2 = x+(p0+p1+b2); x3 = LN2(x2)+x2 (in regs) -> x3h + router ========
__global__ __launch_bounds__(256) void resln2_router_kernel(
    const float* __restrict__ x, const float* __restrict__ p0,
    const float* __restrict__ p1, const float* __restrict__ b2,
    const float* __restrict__ g, const float* __restrict__ b,
    const float* __restrict__ wrm,
    half_t* __restrict__ x3h,
    int* __restrict__ cnt, int* __restrict__ aid, float* __restrict__ gate)
{
    __shared__ float wl[NEXP][DIM];
    __shared__ int   texp[RBLK * 2];
    __shared__ float tgate[RBLK * 2];
    __shared__ int   lslot[RBLK * 2];
    __shared__ int   lcnt[NEXP], lbase[NEXP];
    const int tid = threadIdx.x;
    for (int i = tid; i < NEXP * DIM / 4; i += 256)
        reinterpret_cast<float4*>(&wl[0][0])[i] = reinterpret_cast<const float4*>(wrm)[i];
    if (tid < NEXP) lcnt[tid] = 0;
    __syncthreads();
    const int w = tid >> 6, lane = tid & 63;
    const int d0 = lane * 8;
    float wle[NEXP][8];
#pragma unroll
    for (int e = 0; e < NEXP; e++)
#pragma unroll
        for (int j = 0; j < 8; j++) wle[e][j] = wl[e][d0 + j];
    float gg[8], bb[8], b2v[8];
#pragma unroll
    for (int j = 0; j < 8; j++) { gg[j] = g[d0 + j]; bb[j] = b[d0 + j]; b2v[j] = b2[d0 + j]; }
#pragma unroll 1
    for (int t = 0; t < RBLK / 4; ++t) {
        const int lt = w * (RBLK / 4) + t;
        const int token = blockIdx.x * RBLK + lt;
        const size_t base = (size_t)token * DIM + d0;
        float z[8];
#pragma unroll
        for (int h = 0; h < 2; h++) {
            float4 xa = reinterpret_cast<const float4*>(x + base)[h];
            float4 pa = reinterpret_cast<const float4*>(p0 + base)[h];
            float4 qa = reinterpret_cast<const float4*>(p1 + base)[h];
            z[4 * h + 0] = xa.x + pa.x + qa.x + b2v[4 * h + 0];
            z[4 * h + 1] = xa.y + pa.y + qa.y + b2v[4 * h + 1];
            z[4 * h + 2] = xa.z + pa.z + qa.z + b2v[4 * h + 2];
            z[4 * h + 3] = xa.w + pa.w + qa.w + b2v[4 * h + 3];
        }
        float s = 0.f;
#pragma unroll
        for (int j = 0; j < 8; j++) s += z[j];
#pragma unroll
        for (int off = 32; off; off >>= 1) s += __shfl_xor(s, off);
        const float mean = s * (1.0f / DIM);
        float vs = 0.f;
#pragma unroll
        for (int j = 0; j < 8; j++) { float d = z[j] - mean; vs += d * d; }
#pragma unroll
        for (int off = 32; off; off >>= 1) vs += __shfl_xor(vs, off);
        const float rstd = rsqrtf(vs * (1.0f / DIM) + 1e-5f);
        float y[8];
        f16x8 hv;
#pragma unroll
        for (int j = 0; j < 8; j++) {
            y[j] = (z[j] - mean) * rstd * gg[j] + bb[j] + z[j];
            hv[j] = (half_t)y[j];
        }
        *reinterpret_cast<f16x8*>(x3h + base) = hv;
        float a[NEXP];
#pragma unroll
        for (int e = 0; e < NEXP; e++) {
            a[e] = 0.f;
#pragma unroll
            for (int j = 0; j < 8; j++) a[e] += y[j] * wle[e][j];
        }
#pragma unroll
        for (int e = 0; e < NEXP; e++)
#pragma unroll
            for (int off = 32; off; off >>= 1) a[e] += __shfl_xor(a[e], off);
        if (lane == 0) {
            int i1 = 0; float v1 = a[0];
#pragma unroll
            for (int e = 1; e < NEXP; e++) if (a[e] > v1) { v1 = a[e]; i1 = e; }
            int i2 = -1; float v2 = -3.4e38f;
#pragma unroll
            for (int e = 0; e < NEXP; e++) if (e != i1 && a[e] > v2) { v2 = a[e]; i2 = e; }
            float e2 = expf(v2 - v1);
            float g1 = 1.0f / (1.0f + e2);
            texp[lt * 2]     = i1; tgate[lt * 2]     = g1;
            texp[lt * 2 + 1] = i2; tgate[lt * 2 + 1] = 1.0f - g1;
        }
    }
    __syncthreads();
    if (tid < RBLK * 2) lslot[tid] = atomicAdd(&lcnt[texp[tid]], 1);
    __syncthreads();
    if (tid < NEXP) lbase[tid] = atomicAdd(&cnt[tid * 32], lcnt[tid]);
    __syncthreads();
    if (tid < RBLK * 2) {
        const int e = texp[tid];
        const int asg = blockIdx.x * (RBLK * 2) + tid;   // token*2 + k
        aid[e * NTOK + lbase[e] + lslot[tid]] = asg;
        gate[asg] = tgate[tid];
    }
}

// ======== expert GEMMs, 8-wave BM=256/BN=128 counted-vmcnt (best-measured config) ========
// BM=256 (rowmap-gathered), BN=128, 8 waves 4(M)x2(N), per-wave 64x64, BK=32.
// LDS/buffer: A 256x32 (16KB) + B 128x32 (8KB) = 24KB; x2 dbuf = 48KB -> 3 blocks/CU.
// 3 gl16/thread/step; counted vmcnt(3); 2 barriers/step.
// EG=1: He[a] = gelu(X[a>>1] @ W^T + eb).  EG=2: Ye[a] = (Hin[a] @ W^T + eb) * gate[a].
template <int EG, int KDIM, int AROWSHIFT>
__global__ __launch_bounds__(512, 2) void egemm8_kernel(
    const half_t* __restrict__ Ain,
    const half_t* __restrict__ W,
    const float* __restrict__ ebias,
    const int* __restrict__ cnt, const int* __restrict__ aid,
    const float* __restrict__ gate,
    half_t* __restrict__ Oh,
    float* __restrict__ Of,
    int Nc)
{
    const int ntPerE = Nc / 128;                 // 8 (EG1) or 4 (EG2)
    const int bid = blockIdx.x;
    const int e   = bid / (32 * ntPerE);
    const int rem = bid % (32 * ntPerE);
    const int mt  = rem / ntPerE, nt = rem % ntPerE;
    const int ne  = cnt[e * 32];
    if (mt * 256 >= ne) return;

    constexpr int TOT = 8192 + 4096;             // elems per buffer: A 256x32, B 128x32
    __shared__ __align__(16) half_t lds[2 * TOT];
    __shared__ int rowmap[256];
    const int tid = threadIdx.x;
    {
        int slot = mt * 256 + tid;
        if (tid < 256) rowmap[tid] = (slot < ne) ? aid[e * NTOK + slot] : -1;
    }
    __syncthreads();

    const int lane = tid & 63, wid = tid >> 6;
    const int wr = wid >> 1, wc = wid & 1;       // 4 x 2 wave grid
    const int l31 = lane & 31, l5 = lane >> 5;

    // staging: chunks c = tid + 512*i, i<3.  c<1024 -> A (row c>>2), else B.
    const half_t* gsrc[3];
    const half_t* Wb = W + (size_t)e * Nc * KDIM;
#pragma unroll
    for (int i = 0; i < 3; i++) {
        int c = tid + 512 * i;
        if (c < 1024) {
            int r = c >> 2, ss = (c & 3) ^ ((r >> 1) & 3);
            int a = rowmap[r];
            gsrc[i] = Ain + (size_t)(a >= 0 ? (a >> AROWSHIFT) : 0) * KDIM + ss * 8;
        } else {
            int cb = c - 1024;
            int r = cb >> 2, ss = (cb & 3) ^ ((r >> 1) & 3);
            gsrc[i] = Wb + (size_t)(nt * 128 + r) * KDIM + ss * 8;
        }
    }

    int oa[2][2], ob[2][2];
#pragma unroll
    for (int m = 0; m < 2; m++)
#pragma unroll
        for (int kh = 0; kh < 2; kh++) {
            int ra = wr * 64 + m * 32 + l31;
            oa[m][kh] = ra * 32 + (((l5 + 2 * kh) ^ ((ra >> 1) & 3)) << 3);
        }
#pragma unroll
    for (int n = 0; n < 2; n++)
#pragma unroll
        for (int kh = 0; kh < 2; kh++) {
            int rb = wc * 64 + n * 32 + l31;
            ob[n][kh] = 8192 + rb * 32 + (((l5 + 2 * kh) ^ ((rb >> 1) & 3)) << 3);
        }

    f32x16 acc[2][2];
#pragma unroll
    for (int m = 0; m < 2; m++)
#pragma unroll
        for (int n = 0; n < 2; n++)
#pragma unroll
            for (int q = 0; q < 16; q++) acc[m][n][q] = 0.f;

    auto stage = [&](int bsel, int kof) {
#pragma unroll
        for (int i = 0; i < 3; i++)
            gl16(gsrc[i] + kof, &lds[bsel * TOT + (tid + 512 * i) * 8]);
    };
    auto compute = [&](int p) {
        const half_t* buf = &lds[p ? TOT : 0];
        __builtin_amdgcn_s_setprio(1);
#pragma unroll
        for (int kh = 0; kh < 2; kh++) {
            f16x8 a0 = *(const f16x8*)(buf + oa[0][kh]);
            f16x8 a1 = *(const f16x8*)(buf + oa[1][kh]);
            f16x8 b0 = *(const f16x8*)(buf + ob[0][kh]);
            f16x8 b1 = *(const f16x8*)(buf + ob[1][kh]);
            acc[0][0] = MFMA32(a0, b0, acc[0][0]);
            acc[0][1] = MFMA32(a0, b1, acc[0][1]);
            acc[1][0] = MFMA32(a1, b0, acc[1][0]);
            acc[1][1] = MFMA32(a1, b1, acc[1][1]);
        }
        __builtin_amdgcn_s_setprio(0);
    };

    const int nsteps = KDIM / 32;
    stage(0, 0);
#pragma unroll 1
    for (int s = 0; s < nsteps - 1; ++s) {
        stage((s + 1) & 1, (s + 1) * 32);
        asm volatile("s_waitcnt vmcnt(3)" ::: "memory");
        __builtin_amdgcn_s_barrier();
        compute(s & 1);
        __builtin_amdgcn_s_barrier();
    }
    asm volatile("s_waitcnt vmcnt(0)" ::: "memory");
    __builtin_amdgcn_s_barrier();
    compute((nsteps - 1) & 1);

    const int er = 4 * l5;
#pragma unroll
    for (int m = 0; m < 2; m++)
#pragma unroll
        for (int reg = 0; reg < 16; reg++) {
            int rloc = wr * 64 + m * 32 + er + 8 * (reg >> 2) + (reg & 3);
            int a = rowmap[rloc];
            if (a >= 0) {
#pragma unroll
                for (int n = 0; n < 2; n++) {
                    int cc = nt * 128 + wc * 64 + n * 32 + l31;
                    float v = acc[m][n][reg] + ebias[e * Nc + cc];
                    if (EG == 1) {
                        Oh[(size_t)a * Nc + cc] = (half_t)gelu_exact(v);
                    } else {
                        Of[(size_t)a * Nc + cc] = v * gate[a];
                    }
                }
            }
        }
}

// ---------------- combine two expert outputs per token + final LN ----------------
__global__ __launch_bounds__(256) void combine_lnf_kernel(
    const float* __restrict__ Ye, const float* __restrict__ g, const float* __restrict__ b,
    float* __restrict__ out)
{
    const int t = blockIdx.x, tid = threadIdx.x;
    __shared__ float red[4];
    float2 y0 = reinterpret_cast<const float2*>(Ye + (size_t)(2 * t) * DIM)[tid];
    float2 y1 = reinterpret_cast<const float2*>(Ye + (size_t)(2 * t + 1) * DIM)[tid];
    float z0 = y0.x + y1.x, z1 = y0.y + y1.y;
    float mean = block_sum4(z0 + z1, red, tid) * (1.0f / DIM);
    float d0 = z0 - mean, d1 = z1 - mean;
    float var = block_sum4(d0 * d0 + d1 * d1, red, tid) * (1.0f / DIM);
    float rstd = rsqrtf(var + 1e-5f);
    int d = tid * 2;
    out[(size_t)t * DIM + d]     = d0 * rstd * g[d]     + b[d];
    out[(size_t)t * DIM + d + 1] = d1 * rstd * g[d + 1] + b[d + 1];
    if (t == 0 && tid == 0) out[(size_t)NTOK * DIM] = 0.f;  // aux_loss
}

extern "C" void kernel_launch(void* const* d_in, const int* in_sizes, int n_in,
                              void* d_out, int out_size, void* d_ws, size_t ws_size,
                              hipStream_t stream)
{
    (void)in_sizes; (void)n_in; (void)out_size; (void)ws_size;
    const float* x    = (const float*)d_in[0];
    const float* ln1g = (const float*)d_in[1];
    const float* ln1b = (const float*)d_in[2];
    const float* w1   = (const float*)d_in[3];
    const float* b1   = (const float*)d_in[4];
    const float* w2   = (const float*)d_in[5];
    const float* b2   = (const float*)d_in[6];
    const float* ln2g = (const float*)d_in[7];
    const float* ln2b = (const float*)d_in[8];
    const float* wrm  = (const float*)d_in[9];
    const float* ew1  = (const float*)d_in[10];
    const float* eb1  = (const float*)d_in[11];
    const float* ew2  = (const float*)d_in[12];
    const float* eb2  = (const float*)d_in[13];
    const float* lnfg = (const float*)d_in[14];
    const float* lnfb = (const float*)d_in[15];
    float* out = (float*)d_out;

    char* w = (char*)d_ws;
    size_t off = 0;
    auto take = [&](size_t bytes) {
        char* p = w + off;
        off += bytes;
        off = (off + 255) & ~(size_t)255;
        return p;
    };
    half_t* xh_h  = (half_t*)take((size_t)NTOK * DIM * 2);   // also split-K partial p1 (f32, 16MB)
    half_t* xh_l  = (half_t*)take((size_t)NTOK * DIM * 2);
    half_t* w1t_h = (half_t*)take((size_t)DIM * MHID * 2);
    half_t* w1t_l = (half_t*)take((size_t)DIM * MHID * 2);
    half_t* w2t_h = (half_t*)take((size_t)MHID * DIM * 2);
    half_t* w2t_l = (half_t*)take((size_t)MHID * DIM * 2);
    char*   big   = take((size_t)NTOK * MHID * 2 * 2);        // 64 MiB: a1 hi/lo, later He + Ye
    half_t* a1h   = (half_t*)big;
    half_t* a1l   = (half_t*)(big + (size_t)NTOK * MHID * 2);
    half_t* heh   = (half_t*)big;                              // alias (a1 dead after gemm8<0>)
    float*  yef   = (float*)(big + (size_t)NTOK * MHID * 2);   // alias
    float*  p0f   = (float*)take((size_t)NTOK * DIM * 4);      // split-K partial p0
    half_t* x3h   = (half_t*)take((size_t)NTOK * DIM * 2);
    half_t* ew1t  = (half_t*)take((size_t)NEXP * DIM * EHID * 2);
    half_t* ew2t  = (half_t*)take((size_t)NEXP * EHID * DIM * 2);
    int*    cnt   = (int*)take(1024);                          // 8 experts, 128 B apart
    int*    aid   = (int*)take((size_t)NEXP * NTOK * 4);
    float*  gate  = (float*)take((size_t)NTOK * 2 * 4);

    float* p0 = p0f;
    float* p1 = (float*)xh_h;   // xh_h+xh_l = contiguous 16 MB, dead after gemm8<1>

    ln1_split_kernel<<<NTOK, 256, 0, stream>>>(x, ln1g, ln1b, xh_h, xh_l, cnt);
    transpose_all_kernel<<<10240, dim3(32, 8), 0, stream>>>(
        w1, w2, ew1, ew2, w1t_h, w1t_l, w2t_h, w2t_l, ew1t, ew2t);
    // MLP GEMM1: [8192x512] @ [512x2048], gelu, split out.  256x256 tile, 8 waves.
    gemm8_kernel<1, 2><<<dim3(NTOK / 256, MHID / 256, 1), 512, 0, stream>>>(
        xh_h, xh_l, w1t_h, w1t_l, b1, (float*)0, (float*)0, a1h, a1l, MHID, DIM, DIM);
    // MLP GEMM2: [8192x2048] @ [2048x512], 256x128 tile, split-K=2 raw partials
    gemm8_kernel<0, 1><<<dim3(NTOK / 256, DIM / 128, 2), 512, 0, stream>>>(
        a1h, a1l, w2t_h, w2t_l, (const float*)0, p0, p1, (half_t*)0, (half_t*)0, DIM, MHID, MHID / 2);
    // fused residual + LN2 + router (x3 lives in registers; writes x3h only)
    resln2_router_kernel<<<NTOK / RBLK, 256, 0, stream>>>(
        x, p0, p1, b2, ln2g, ln2b, wrm, x3h, cnt, aid, gate);
    // expert GEMM1: 8 experts x 32 m-tiles x 8 n-tiles (BM=256/BN=128, 3 blocks/CU)
    egemm8_kernel<1, DIM, 1><<<NEXP * 32 * (EHID / 128), 512, 0, stream>>>(
        x3h, ew1t, eb1, cnt, aid, (const float*)0, heh, (float*)0, EHID);
    // expert GEMM2: 8 experts x 32 m-tiles x 4 n-tiles
    egemm8_kernel<2, EHID, 0><<<NEXP * 32 * (DIM / 128), 512, 0, stream>>>(
        heh, ew2t, eb2, cnt, aid, gate, (half_t*)0, yef, DIM);
    combine_lnf_kernel<<<NTOK, 256, 0, stream>>>(yef, lnfg, lnfb, out);
}

// Round 16
// 304.587 us; speedup vs baseline: 1.1028x; 1.0050x over previous
//
#include <hip/hip_runtime.h>

#define NTOK 8192
#define DIM  512
#define MHID 2048
#define EHID 1024
#define NEXP 8
#define RBLK 64   // tokens per router block

using half_t = _Float16;
typedef _Float16 f16x8 __attribute__((ext_vector_type(8)));
typedef float    f32x16 __attribute__((ext_vector_type(16)));

#define MFMA32(a, b, c) __builtin_amdgcn_mfma_f32_32x32x16_f16((a), (b), (c), 0, 0, 0)

typedef const __attribute__((address_space(1))) void* gas_ptr;
typedef __attribute__((address_space(3))) void*       las_ptr;
__device__ __forceinline__ void gl16(const void* g, void* l) {
    __builtin_amdgcn_global_load_lds((gas_ptr)g, (las_ptr)l, 16, 0, 0);
}

__device__ __forceinline__ float gelu_exact(float v) {
    return 0.5f * v * (1.0f + erff(v * 0.70710678118654752f));
}

// all-threads-return block sum over 4 waves (256 threads)
__device__ __forceinline__ float block_sum4(float v, float* red, int tid) {
#pragma unroll
    for (int off = 32; off; off >>= 1) v += __shfl_down(v, off);
    if ((tid & 63) == 0) red[tid >> 6] = v;
    __syncthreads();
    float r = red[0] + red[1] + red[2] + red[3];
    __syncthreads();
    return r;
}

// ==== FUSED prelude: blocks [0,10240) = weight transposes; [10240,18432) = LN1 ====
// Both are dependency-free preludes to MLP GEMM1; one launch instead of two.
__global__ void prelude_kernel(
    const float* __restrict__ x, const float* __restrict__ ln1g, const float* __restrict__ ln1b,
    const float* __restrict__ w1, const float* __restrict__ w2,
    const float* __restrict__ ew1, const float* __restrict__ ew2,
    half_t* __restrict__ xh, half_t* __restrict__ xl, int* __restrict__ cnt,
    half_t* __restrict__ w1t_h, half_t* __restrict__ w1t_l,
    half_t* __restrict__ w2t_h, half_t* __restrict__ w2t_l,
    half_t* __restrict__ ew1t, half_t* __restrict__ ew2t)
{
    const int tid = threadIdx.y * 32 + threadIdx.x;
    if (blockIdx.x >= 10240) {
        // ---------------- LN1 + fp16 hi/lo split (+ cnt zeroing) ----------------
        const int row = blockIdx.x - 10240;
        if (row == 0) cnt[tid] = 0;   // zero all 256 padded slots
        __shared__ float red[4];
        const size_t base = (size_t)row * DIM;
        float2 v = reinterpret_cast<const float2*>(x + base)[tid];
        float mean = block_sum4(v.x + v.y, red, tid) * (1.0f / DIM);
        float d0 = v.x - mean, d1 = v.y - mean;
        float var = block_sum4(d0 * d0 + d1 * d1, red, tid) * (1.0f / DIM);
        float rstd = rsqrtf(var + 1e-5f);
        int d = tid * 2;
        float y0 = d0 * rstd * ln1g[d]     + ln1b[d];
        float y1 = d1 * rstd * ln1g[d + 1] + ln1b[d + 1];
        half_t h0 = (half_t)y0, h1 = (half_t)y1;
        xh[base + d] = h0;  xh[base + d + 1] = h1;
        xl[base + d]     = (half_t)(y0 - (float)h0);
        xl[base + d + 1] = (half_t)(y1 - (float)h1);
        return;
    }
    // ---------------- transposes: [R][C] -> [C][R], f16 (optional lo split) ----------------
    int bb = blockIdx.x;
    const float* in; half_t* oh; half_t* ol = (half_t*)0;
    int R, C, cx, cy; size_t mo = 0;
    if (bb < 1024)      { in = w1;  oh = w1t_h; ol = w1t_l; R = 512;  C = 2048; cx = bb & 63; cy = bb >> 6; }
    else if (bb < 2048) { bb -= 1024; in = w2;  oh = w2t_h; ol = w2t_l; R = 2048; C = 512; cx = bb & 15; cy = bb >> 4; }
    else if (bb < 6144) { bb -= 2048; int e = bb >> 9, r = bb & 511;
                          in = ew1; oh = ew1t; R = 512;  C = 1024; mo = (size_t)e * R * C; cx = r & 31; cy = r >> 5; }
    else                { bb -= 6144; int e = bb >> 9, r = bb & 511;
                          in = ew2; oh = ew2t; R = 1024; C = 512;  mo = (size_t)e * R * C; cx = r & 15; cy = r >> 4; }
    __shared__ float t[32][33];
    const int c0 = cx * 32, r0 = cy * 32;
    const int tx = threadIdx.x, ty = threadIdx.y;
    for (int i = ty; i < 32; i += 8) t[i][tx] = in[mo + (size_t)(r0 + i) * C + c0 + tx];
    __syncthreads();
    for (int i = ty; i < 32; i += 8) {
        float v = t[tx][i];
        size_t o = mo + (size_t)(c0 + i) * R + r0 + tx;
        half_t h = (half_t)v;
        oh[o] = h;
        if (ol) ol[o] = (half_t)(v - (float)h);
    }
}

// ======== split-3 f16 MFMA GEMM, 256-row tile, 8 waves, counted-vmcnt, 2 barriers/step ========
// (r9 structure — empirically at this structure's ceiling; seven schedule variants tied)
template <int EPI, int NREP>
__global__ __launch_bounds__(512, 2) void gemm8_kernel(
    const half_t* __restrict__ A0, const half_t* __restrict__ A1,
    const half_t* __restrict__ B0, const half_t* __restrict__ B1,
    const float* __restrict__ bias,
    float* __restrict__ Cf0, float* __restrict__ Cf1,
    half_t* __restrict__ Ch, half_t* __restrict__ Cl,
    int Nc, int K, int Ktile)
{
    constexpr int BN    = NREP * 128;
    constexpr int LOADS = 4 + 2 * NREP;            // 16B chunks staged per thread per K-step
    constexpr int TOT   = 16384 + NREP * 8192;     // half_t elems per LDS buffer
    __shared__ __align__(16) half_t lds[2 * TOT];

    const int m0 = blockIdx.x * 256, n0 = blockIdx.y * BN;
    const int kbeg = blockIdx.z * Ktile;
    float* Cf = blockIdx.z ? Cf1 : Cf0;
    const int tid = threadIdx.x;
    const int lane = tid & 63, wid = tid >> 6;
    const int wr = wid >> 2, wc = wid & 3;         // 2 x 4 wave grid
    const int l31 = lane & 31, l5 = lane >> 5;

    const half_t* gsrc[LOADS];
    {
        const half_t* A0p = A0 + (size_t)m0 * K + kbeg;
        const half_t* A1p = A1 + (size_t)m0 * K + kbeg;
        const half_t* B0p = B0 + (size_t)n0 * K + kbeg;
        const half_t* B1p = B1 + (size_t)n0 * K + kbeg;
#pragma unroll
        for (int i = 0; i < LOADS; i++) {
            int c = tid + 512 * i;
            const half_t* base; int cm;
            if (c < 1024)                  { base = A0p; cm = c; }
            else if (c < 2048)             { base = A1p; cm = c - 1024; }
            else if (c < 2048 + NREP * 512){ base = B0p; cm = c - 2048; }
            else                           { base = B1p; cm = c - 2048 - NREP * 512; }
            int r = cm >> 2, ss = (cm & 3) ^ ((r >> 1) & 3);
            gsrc[i] = base + (size_t)r * K + ss * 8;
        }
    }

    int oa[4][2], ob[NREP][2];
#pragma unroll
    for (int m = 0; m < 4; m++)
#pragma unroll
        for (int kh = 0; kh < 2; kh++) {
            int ra = wr * 128 + m * 32 + l31;
            oa[m][kh] = ra * 32 + (((l5 + 2 * kh) ^ ((ra >> 1) & 3)) << 3);
        }
#pragma unroll
    for (int n = 0; n < NREP; n++)
#pragma unroll
        for (int kh = 0; kh < 2; kh++) {
            int rb = wc * (NREP * 32) + n * 32 + l31;
            ob[n][kh] = rb * 32 + (((l5 + 2 * kh) ^ ((rb >> 1) & 3)) << 3);
        }

    f32x16 acc[4][NREP];
#pragma unroll
    for (int m = 0; m < 4; m++)
#pragma unroll
        for (int n = 0; n < NREP; n++)
#pragma unroll
            for (int q = 0; q < 16; q++) acc[m][n][q] = 0.f;

    auto stage = [&](int bsel, int kof) {
#pragma unroll
        for (int i = 0; i < LOADS; i++)
            gl16(gsrc[i] + kof, &lds[bsel * TOT + (tid + 512 * i) * 8]);
    };
    auto compute = [&](int p) {
        const half_t* buf = &lds[p ? TOT : 0];
        __builtin_amdgcn_s_setprio(1);
#pragma unroll
        for (int kh = 0; kh < 2; kh++) {
            f16x8 ah[4], al[4], bh[NREP], bl[NREP];
#pragma unroll
            for (int m = 0; m < 4; m++) {
                ah[m] = *(const f16x8*)(buf + oa[m][kh]);
                al[m] = *(const f16x8*)(buf + 8192 + oa[m][kh]);
            }
#pragma unroll
            for (int n = 0; n < NREP; n++) {
                bh[n] = *(const f16x8*)(buf + 16384 + ob[n][kh]);
                bl[n] = *(const f16x8*)(buf + 16384 + BN * 32 + ob[n][kh]);
            }
#pragma unroll
            for (int m = 0; m < 4; m++)
#pragma unroll
                for (int n = 0; n < NREP; n++) {
                    acc[m][n] = MFMA32(ah[m], bh[n], acc[m][n]);
                    acc[m][n] = MFMA32(al[m], bh[n], acc[m][n]);
                    acc[m][n] = MFMA32(ah[m], bl[n], acc[m][n]);
                }
        }
        __builtin_amdgcn_s_setprio(0);
    };

    const int nsteps = Ktile / 32;
    stage(0, 0);
#pragma unroll 1
    for (int s = 0; s < nsteps - 1; ++s) {
        stage((s + 1) & 1, (s + 1) * 32);
        if constexpr (NREP == 2) asm volatile("s_waitcnt vmcnt(8)" ::: "memory");
        else                     asm volatile("s_waitcnt vmcnt(6)" ::: "memory");
        __builtin_amdgcn_s_barrier();
        compute(s & 1);
        __builtin_amdgcn_s_barrier();
    }
    asm volatile("s_waitcnt vmcnt(0)" ::: "memory");
    __builtin_amdgcn_s_barrier();
    compute((nsteps - 1) & 1);

    const int er = 4 * l5;
#pragma unroll
    for (int m = 0; m < 4; m++)
#pragma unroll
        for (int n = 0; n < NREP; n++) {
            int cc = n0 + wc * (NREP * 32) + n * 32 + l31;
            float bv = (EPI == 1) ? bias[cc] : 0.f;
#pragma unroll
            for (int reg = 0; reg < 16; reg++) {
                int rr = m0 + wr * 128 + m * 32 + er + 8 * (reg >> 2) + (reg & 3);
                float v = acc[m][n][reg] + bv;
                size_t o = (size_t)rr * Nc + cc;
                if (EPI == 1) {
                    float ge = gelu_exact(v);
                    half_t h = (half_t)ge;
                    Ch[o] = h;
                    Cl[o] = (half_t)(ge - (float)h);
                } else {
                    Cf[o] = v;
                }
            }
        }
}

// ======== FUSED: x2 = x+(p0+p1+b2); x3 = LN2(x2)+x2 (in regs) -> x3h + router ========
__global__ __launch_bounds__(256) void resln2_router_kernel(
    const float* __restrict__ x, const float* __restrict__ p0,
    const float* __restrict__ p1, const float* __restrict__ b2,
    const float* __restrict__ g, const float* __restrict__ b,
    const float* __restrict__ wrm,
    half_t* __restrict__ x3h,
    int* __restrict__ cnt, int* __restrict__ aid, float* __restrict__ gate)
{
    __shared__ float wl[NEXP][DIM];
    __shared__ int   texp[RBLK * 2];
    __shared__ float tgate[RBLK * 2];
    __shared__ int   lslot[RBLK * 2];
    __shared__ int   lcnt[NEXP], lbase[NEXP];
    const int tid = threadIdx.x;
    for (int i = tid; i < NEXP * DIM / 4; i += 256)
        reinterpret_cast<float4*>(&wl[0][0])[i] = reinterpret_cast<const float4*>(wrm)[i];
    if (tid < NEXP) lcnt[tid] = 0;
    __syncthreads();
    const int w = tid >> 6, lane = tid & 63;
    const int d0 = lane * 8;
    float wle[NEXP][8];
#pragma unroll
    for (int e = 0; e < NEXP; e++)
#pragma unroll
        for (int j = 0; j < 8; j++) wle[e][j] = wl[e][d0 + j];
    float gg[8], bb[8], b2v[8];
#pragma unroll
    for (int j = 0; j < 8; j++) { gg[j] = g[d0 + j]; bb[j] = b[d0 + j]; b2v[j] = b2[d0 + j]; }
#pragma unroll 1
    for (int t = 0; t < RBLK / 4; ++t) {
        const int lt = w * (RBLK / 4) + t;
        const int token = blockIdx.x * RBLK + lt;
        const size_t base = (size_t)token * DIM + d0;
        float z[8];
#pragma unroll
        for (int h = 0; h < 2; h++) {
            float4 xa = reinterpret_cast<const float4*>(x + base)[h];
            float4 pa = reinterpret_cast<const float4*>(p0 + base)[h];
            float4 qa = reinterpret_cast<const float4*>(p1 + base)[h];
            z[4 * h + 0] = xa.x + pa.x + qa.x + b2v[4 * h + 0];
            z[4 * h + 1] = xa.y + pa.y + qa.y + b2v[4 * h + 1];
            z[4 * h + 2] = xa.z + pa.z + qa.z + b2v[4 * h + 2];
            z[4 * h + 3] = xa.w + pa.w + qa.w + b2v[4 * h + 3];
        }
        float s = 0.f;
#pragma unroll
        for (int j = 0; j < 8; j++) s += z[j];
#pragma unroll
        for (int off = 32; off; off >>= 1) s += __shfl_xor(s, off);
        const float mean = s * (1.0f / DIM);
        float vs = 0.f;
#pragma unroll
        for (int j = 0; j < 8; j++) { float d = z[j] - mean; vs += d * d; }
#pragma unroll
        for (int off = 32; off; off >>= 1) vs += __shfl_xor(vs, off);
        const float rstd = rsqrtf(vs * (1.0f / DIM) + 1e-5f);
        float y[8];
        f16x8 hv;
#pragma unroll
        for (int j = 0; j < 8; j++) {
            y[j] = (z[j] - mean) * rstd * gg[j] + bb[j] + z[j];
            hv[j] = (half_t)y[j];
        }
        *reinterpret_cast<f16x8*>(x3h + base) = hv;
        float a[NEXP];
#pragma unroll
        for (int e = 0; e < NEXP; e++) {
            a[e] = 0.f;
#pragma unroll
            for (int j = 0; j < 8; j++) a[e] += y[j] * wle[e][j];
        }
#pragma unroll
        for (int e = 0; e < NEXP; e++)
#pragma unroll
            for (int off = 32; off; off >>= 1) a[e] += __shfl_xor(a[e], off);
        if (lane == 0) {
            int i1 = 0; float v1 = a[0];
#pragma unroll
            for (int e = 1; e < NEXP; e++) if (a[e] > v1) { v1 = a[e]; i1 = e; }
            int i2 = -1; float v2 = -3.4e38f;
#pragma unroll
            for (int e = 0; e < NEXP; e++) if (e != i1 && a[e] > v2) { v2 = a[e]; i2 = e; }
            float e2 = expf(v2 - v1);
            float g1 = 1.0f / (1.0f + e2);
            texp[lt * 2]     = i1; tgate[lt * 2]     = g1;
            texp[lt * 2 + 1] = i2; tgate[lt * 2 + 1] = 1.0f - g1;
        }
    }
    __syncthreads();
    if (tid < RBLK * 2) lslot[tid] = atomicAdd(&lcnt[texp[tid]], 1);
    __syncthreads();
    if (tid < NEXP) lbase[tid] = atomicAdd(&cnt[tid * 32], lcnt[tid]);
    __syncthreads();
    if (tid < RBLK * 2) {
        const int e = texp[tid];
        const int asg = blockIdx.x * (RBLK * 2) + tid;   // token*2 + k
        aid[e * NTOK + lbase[e] + lslot[tid]] = asg;
        gate[asg] = tgate[tid];
    }
}

// ======== expert GEMMs, 8-wave BM=256/BN=128 counted-vmcnt (best-measured config) ========
// EG=1: He[a] = gelu(X[a>>1] @ W^T + eb) -> f16.  EG=2: Ye[a] = (Hin[a] @ W^T + eb)*gate -> f16.
template <int EG, int KDIM, int AROWSHIFT>
__global__ __launch_bounds__(512, 2) void egemm8_kernel(
    const half_t* __restrict__ Ain,
    const half_t* __restrict__ W,
    const float* __restrict__ ebias,
    const int* __restrict__ cnt, const int* __restrict__ aid,
    const float* __restrict__ gate,
    half_t* __restrict__ Oh,
    int Nc)
{
    const int ntPerE = Nc / 128;                 // 8 (EG1) or 4 (EG2)
    const int bid = blockIdx.x;
    const int e   = bid / (32 * ntPerE);
    const int rem = bid % (32 * ntPerE);
    const int mt  = rem / ntPerE, nt = rem % ntPerE;
    const int ne  = cnt[e * 32];
    if (mt * 256 >= ne) return;

    constexpr int TOT = 8192 + 4096;             // elems per buffer: A 256x32, B 128x32
    __shared__ __align__(16) half_t lds[2 * TOT];
    __shared__ int rowmap[256];
    const int tid = threadIdx.x;
    {
        int slot = mt * 256 + tid;
        if (tid < 256) rowmap[tid] = (slot < ne) ? aid[e * NTOK + slot] : -1;
    }
    __syncthreads();

    const int lane = tid & 63, wid = tid >> 6;
    const int wr = wid >> 1, wc = wid & 1;       // 4 x 2 wave grid
    const int l31 = lane & 31, l5 = lane >> 5;

    const half_t* gsrc[3];
    const half_t* Wb = W + (size_t)e * Nc * KDIM;
#pragma unroll
    for (int i = 0; i < 3; i++) {
        int c = tid + 512 * i;
        if (c < 1024) {
            int r = c >> 2, ss = (c & 3) ^ ((r >> 1) & 3);
            int a = rowmap[r];
            gsrc[i] = Ain + (size_t)(a >= 0 ? (a >> AROWSHIFT) : 0) * KDIM + ss * 8;
        } else {
            int cb = c - 1024;
            int r = cb >> 2, ss = (cb & 3) ^ ((r >> 1) & 3);
            gsrc[i] = Wb + (size_t)(nt * 128 + r) * KDIM + ss * 8;
        }
    }

    int oa[2][2], ob[2][2];
#pragma unroll
    for (int m = 0; m < 2; m++)
#pragma unroll
        for (int kh = 0; kh < 2; kh++) {
            int ra = wr * 64 + m * 32 + l31;
            oa[m][kh] = ra * 32 + (((l5 + 2 * kh) ^ ((ra >> 1) & 3)) << 3);
        }
#pragma unroll
    for (int n = 0; n < 2; n++)
#pragma unroll
        for (int kh = 0; kh < 2; kh++) {
            int rb = wc * 64 + n * 32 + l31;
            ob[n][kh] = 8192 + rb * 32 + (((l5 + 2 * kh) ^ ((rb >> 1) & 3)) << 3);
        }

    f32x16 acc[2][2];
#pragma unroll
    for (int m = 0; m < 2; m++)
#pragma unroll
        for (int n = 0; n < 2; n++)
#pragma unroll
            for (int q = 0; q < 16; q++) acc[m][n][q] = 0.f;

    auto stage = [&](int bsel, int kof) {
#pragma unroll
        for (int i = 0; i < 3; i++)
            gl16(gsrc[i] + kof, &lds[bsel * TOT + (tid + 512 * i) * 8]);
    };
    auto compute = [&](int p) {
        const half_t* buf = &lds[p ? TOT : 0];
        __builtin_amdgcn_s_setprio(1);
#pragma unroll
        for (int kh = 0; kh < 2; kh++) {
            f16x8 a0 = *(const f16x8*)(buf + oa[0][kh]);
            f16x8 a1 = *(const f16x8*)(buf + oa[1][kh]);
            f16x8 b0 = *(const f16x8*)(buf + ob[0][kh]);
            f16x8 b1 = *(const f16x8*)(buf + ob[1][kh]);
            acc[0][0] = MFMA32(a0, b0, acc[0][0]);
            acc[0][1] = MFMA32(a0, b1, acc[0][1]);
            acc[1][0] = MFMA32(a1, b0, acc[1][0]);
            acc[1][1] = MFMA32(a1, b1, acc[1][1]);
        }
        __builtin_amdgcn_s_setprio(0);
    };

    const int nsteps = KDIM / 32;
    stage(0, 0);
#pragma unroll 1
    for (int s = 0; s < nsteps - 1; ++s) {
        stage((s + 1) & 1, (s + 1) * 32);
        asm volatile("s_waitcnt vmcnt(3)" ::: "memory");
        __builtin_amdgcn_s_barrier();
        compute(s & 1);
        __builtin_amdgcn_s_barrier();
    }
    asm volatile("s_waitcnt vmcnt(0)" ::: "memory");
    __builtin_amdgcn_s_barrier();
    compute((nsteps - 1) & 1);

    const int er = 4 * l5;
#pragma unroll
    for (int m = 0; m < 2; m++)
#pragma unroll
        for (int reg = 0; reg < 16; reg++) {
            int rloc = wr * 64 + m * 32 + er + 8 * (reg >> 2) + (reg & 3);
            int a = rowmap[rloc];
            if (a >= 0) {
#pragma unroll
                for (int n = 0; n < 2; n++) {
                    int cc = nt * 128 + wc * 64 + n * 32 + l31;
                    float v = acc[m][n][reg] + ebias[e * Nc + cc];
                    if (EG == 1) {
                        Oh[(size_t)a * Nc + cc] = (half_t)gelu_exact(v);
                    } else {
                        Oh[(size_t)a * Nc + cc] = (half_t)(v * gate[a]);
                    }
                }
            }
        }
}

// ---------------- combine two expert outputs (f16) per token + final LN ----------------
__global__ __launch_bounds__(256) void combine_lnf_kernel(
    const half_t* __restrict__ Ye, const float* __restrict__ g, const float* __restrict__ b,
    float* __restrict__ out)
{
    const int t = blockIdx.x, tid = threadIdx.x;
    __shared__ float red[4];
    const int d0 = tid * 2;
    half_t a0 = Ye[(size_t)(2 * t) * DIM + d0];
    half_t a1 = Ye[(size_t)(2 * t) * DIM + d0 + 1];
    half_t c0 = Ye[(size_t)(2 * t + 1) * DIM + d0];
    half_t c1 = Ye[(size_t)(2 * t + 1) * DIM + d0 + 1];
    float z0 = (float)a0 + (float)c0, z1 = (float)a1 + (float)c1;
    float mean = block_sum4(z0 + z1, red, tid) * (1.0f / DIM);
    float e0 = z0 - mean, e1 = z1 - mean;
    float var = block_sum4(e0 * e0 + e1 * e1, red, tid) * (1.0f / DIM);
    float rstd = rsqrtf(var + 1e-5f);
    out[(size_t)t * DIM + d0]     = e0 * rstd * g[d0]     + b[d0];
    out[(size_t)t * DIM + d0 + 1] = e1 * rstd * g[d0 + 1] + b[d0 + 1];
    if (t == 0 && tid == 0) out[(size_t)NTOK * DIM] = 0.f;  // aux_loss
}

extern "C" void kernel_launch(void* const* d_in, const int* in_sizes, int n_in,
                              void* d_out, int out_size, void* d_ws, size_t ws_size,
                              hipStream_t stream)
{
    (void)in_sizes; (void)n_in; (void)out_size; (void)ws_size;
    const float* x    = (const float*)d_in[0];
    const float* ln1g = (const float*)d_in[1];
    const float* ln1b = (const float*)d_in[2];
    const float* w1   = (const float*)d_in[3];
    const float* b1   = (const float*)d_in[4];
    const float* w2   = (const float*)d_in[5];
    const float* b2   = (const float*)d_in[6];
    const float* ln2g = (const float*)d_in[7];
    const float* ln2b = (const float*)d_in[8];
    const float* wrm  = (const float*)d_in[9];
    const float* ew1  = (const float*)d_in[10];
    const float* eb1  = (const float*)d_in[11];
    const float* ew2  = (const float*)d_in[12];
    const float* eb2  = (const float*)d_in[13];
    const float* lnfg = (const float*)d_in[14];
    const float* lnfb = (const float*)d_in[15];
    float* out = (float*)d_out;

    char* w = (char*)d_ws;
    size_t off = 0;
    auto take = [&](size_t bytes) {
        char* p = w + off;
        off += bytes;
        off = (off + 255) & ~(size_t)255;
        return p;
    };
    half_t* xh_h  = (half_t*)take((size_t)NTOK * DIM * 2);   // also split-K partial p1 (f32, 16MB)
    half_t* xh_l  = (half_t*)take((size_t)NTOK * DIM * 2);
    half_t* w1t_h = (half_t*)take((size_t)DIM * MHID * 2);
    half_t* w1t_l = (half_t*)take((size_t)DIM * MHID * 2);
    half_t* w2t_h = (half_t*)take((size_t)MHID * DIM * 2);
    half_t* w2t_l = (half_t*)take((size_t)MHID * DIM * 2);
    char*   big   = take((size_t)NTOK * MHID * 2 * 2);        // 64 MiB: a1 hi/lo, later He + Ye
    half_t* a1h   = (half_t*)big;
    half_t* a1l   = (half_t*)(big + (size_t)NTOK * MHID * 2);
    half_t* heh   = (half_t*)big;                              // alias (a1 dead after gemm8<0>)
    half_t* yeh   = (half_t*)(big + (size_t)NTOK * MHID * 2);  // alias (f16 now)
    float*  p0f   = (float*)take((size_t)NTOK * DIM * 4);      // split-K partial p0
    half_t* x3h   = (half_t*)take((size_t)NTOK * DIM * 2);
    half_t* ew1t  = (half_t*)take((size_t)NEXP * DIM * EHID * 2);
    half_t* ew2t  = (half_t*)take((size_t)NEXP * EHID * DIM * 2);
    int*    cnt   = (int*)take(1024);                          // 8 experts, 128 B apart
    int*    aid   = (int*)take((size_t)NEXP * NTOK * 4);
    float*  gate  = (float*)take((size_t)NTOK * 2 * 4);

    float* p0 = p0f;
    float* p1 = (float*)xh_h;   // xh_h+xh_l = contiguous 16 MB, dead after gemm8<1>

    // fused LN1 + all weight transposes (one launch)
    prelude_kernel<<<10240 + NTOK, dim3(32, 8), 0, stream>>>(
        x, ln1g, ln1b, w1, w2, ew1, ew2,
        xh_h, xh_l, cnt, w1t_h, w1t_l, w2t_h, w2t_l, ew1t, ew2t);
    // MLP GEMM1: [8192x512] @ [512x2048], gelu, split out.  256x256 tile, 8 waves.
    gemm8_kernel<1, 2><<<dim3(NTOK / 256, MHID / 256, 1), 512, 0, stream>>>(
        xh_h, xh_l, w1t_h, w1t_l, b1, (float*)0, (float*)0, a1h, a1l, MHID, DIM, DIM);
    // MLP GEMM2: [8192x2048] @ [2048x512], 256x128 tile, split-K=2 raw partials
    gemm8_kernel<0, 1><<<dim3(NTOK / 256, DIM / 128, 2), 512, 0, stream>>>(
        a1h, a1l, w2t_h, w2t_l, (const float*)0, p0, p1, (half_t*)0, (half_t*)0, DIM, MHID, MHID / 2);
    // fused residual + LN2 + router (x3 lives in registers; writes x3h only)
    resln2_router_kernel<<<NTOK / RBLK, 256, 0, stream>>>(
        x, p0, p1, b2, ln2g, ln2b, wrm, x3h, cnt, aid, gate);
    // expert GEMM1: 8 experts x 32 m-tiles x 8 n-tiles (BM=256/BN=128, 3 blocks/CU)
    egemm8_kernel<1, DIM, 1><<<NEXP * 32 * (EHID / 128), 512, 0, stream>>>(
        x3h, ew1t, eb1, cnt, aid, (const float*)0, heh, EHID);
    // expert GEMM2: 8 experts x 32 m-tiles x 4 n-tiles -> f16 Ye
    egemm8_kernel<2, EHID, 0><<<NEXP * 32 * (DIM / 128), 512, 0, stream>>>(
        heh, ew2t, eb2, cnt, aid, gate, yeh, DIM);
    combine_lnf_kernel<<<NTOK, 256, 0, stream>>>(yeh, lnfg, lnfb, out);
}